// Round 16
// baseline (999.682 us; speedup 1.0000x reference)
//
#include <hip/hip_runtime.h>
#include <hip/hip_bf16.h>

// SearchPredictModel round 16:
//  - build_gm folded into fused kernel's main path (phase 1 per block builds
//    its own 15 G-tiles, dt kept in LDS; phase 2 recurrence). Removes the
//    serial build_gm launch from the critical path -> cont starts earlier.
//  - main recurrence kt loop: #pragma unroll 2 (bounds B-fragment buffering,
//    kills the persistent ~50MB scratch spill of R11/R14/R15).

#define PAD_TOK 200000
#define DD 128
#define HH 256
#define KK 15
#define BB 512
#define SS 16
#define II 64

typedef __bf16 bf16x8 __attribute__((ext_vector_type(8)));
typedef __bf16 bf16x4 __attribute__((ext_vector_type(4)));
typedef float f32x4 __attribute__((ext_vector_type(4)));
#define MFMA16 __builtin_amdgcn_mfma_f32_16x16x32_bf16
#define MFMA8 __builtin_amdgcn_mfma_f32_16x16x32_fp8_fp8

__device__ __forceinline__ float sigm(float x) { return 1.f / (1.f + __expf(-x)); }
__device__ __forceinline__ float tanh_fast(float x) {
  x = fminf(fmaxf(x, -15.f), 15.f);
  float e2 = __expf(2.f * x);
  return (e2 - 1.f) / (e2 + 1.f);
}
__device__ __forceinline__ float bfu(unsigned u16) { return __uint_as_float(u16 << 16); }

// float -> fp8 e4m3 (OCP), RNE, FTZ below 2^-6 (software fallback)
__device__ __forceinline__ unsigned char f2fp8(float x) {
  unsigned u = __float_as_uint(x);
  unsigned s = (u >> 31) << 7;
  int e = (int)((u >> 23) & 0xff) - 127;
  if (e < -6) return (unsigned char)s;
  unsigned m = (u >> 20) & 7;
  unsigned rest = u & 0xFFFFF;
  if (rest > 0x80000 || (rest == 0x80000 && (m & 1))) {
    ++m;
    if (m == 8) {
      m = 0;
      ++e;
    }
  }
  if (e > 7) {
    e = 7;
    m = 6;
  }
  return (unsigned char)(s | ((unsigned)(e + 7) << 3) | m);
}

__device__ __forceinline__ unsigned cvt2fp8(float a, float b) {
#if __has_builtin(__builtin_amdgcn_cvt_pk_fp8_f32)
  return (unsigned)__builtin_amdgcn_cvt_pk_fp8_f32(a, b, 0, false) & 0xffffu;
#else
  return (unsigned)f2fp8(a) | ((unsigned)f2fp8(b) << 8);
#endif
}

// ---------------------------------------------------------------- front end
__global__ __launch_bounds__(128) void k_eself(const int* __restrict__ x,
                                               const int* __restrict__ self_loc,
                                               const float* __restrict__ emb,
                                               float* __restrict__ es,
                                               float* __restrict__ ns) {
  int b = blockIdx.x, d = threadIdx.x;
  int tok = x[((size_t)(b * SS + 0) * II + self_loc[b]) * 8 + 5];
  float v = emb[(size_t)tok * DD + d];
  es[b * DD + d] = v;
  __shared__ float red[128];
  red[d] = v * v;
  __syncthreads();
  for (int o = 64; o > 0; o >>= 1) {
    if (d < o) red[d] += red[d + o];
    __syncthreads();
  }
  if (d == 0) ns[b] = fmaxf(sqrtf(red[0]), 1e-8f);
}

__global__ void k_init(unsigned* minu) { *minu = 0xFFFFFFFFu; }

// one block per row (b,s); 64 items x 4 lanes each
__global__ __launch_bounds__(256) void k_cos(const int* __restrict__ x,
                                             const float* __restrict__ emb,
                                             const float* __restrict__ es,
                                             const float* __restrict__ ns,
                                             float* __restrict__ simw,
                                             unsigned* __restrict__ minu) {
  int row = blockIdx.x;
  int b = row >> 4;
  int tid = threadIdx.x;
  int i = tid >> 2;  // item
  int q = tid & 3;   // dim quarter (32 dims)
  __shared__ float esl[128];
  __shared__ unsigned smin[64];
  if (tid < 128) esl[tid] = es[b * DD + tid];
  __syncthreads();
  const int* xr = x + ((size_t)row * II + i) * 8;
  int tok = xr[5];
  int first = xr[0];
  const float4* ep = (const float4*)(emb + (size_t)tok * DD + q * 32);
  const float4* sp = (const float4*)(esl + q * 32);
  float dot = 0.f, ss = 0.f;
#pragma unroll
  for (int j = 0; j < 8; ++j) {
    float4 a = ep[j];
    float4 e = sp[j];
    dot += a.x * e.x + a.y * e.y + a.z * e.z + a.w * e.w;
    ss += a.x * a.x + a.y * a.y + a.z * a.z + a.w * a.w;
  }
  dot += __shfl_xor(dot, 1);
  ss += __shfl_xor(ss, 1);
  dot += __shfl_xor(dot, 2);
  ss += __shfl_xor(ss, 2);
  if (q == 0) {
    float cosv = dot / (fmaxf(sqrtf(ss), 1e-8f) * ns[b]);
    simw[(size_t)row * II + i] = cosv;
    unsigned key = 0xFFFFFFFFu;
    if (first != PAD_TOK) {
      unsigned u = __float_as_uint(cosv);
      key = (cosv < 0.f) ? ~u : (u | 0x80000000u);
    }
    smin[i] = key;
  }
  __syncthreads();
  if (tid < 64) {
    unsigned m = smin[tid];
    for (int o = 32; o; o >>= 1) m = min(m, __shfl_xor(m, o));
    if (tid == 0 && m != 0xFFFFFFFFu) atomicMin(minu, m);
  }
}

__global__ __launch_bounds__(64) void k_topk(const int* __restrict__ x,
                                             const float* __restrict__ simw,
                                             const unsigned* __restrict__ minu,
                                             int* __restrict__ topidx) {
  int row = blockIdx.x, i = threadIdx.x;
  unsigned mk = *minu;
  float neg = ((mk & 0x80000000u) ? __uint_as_float(mk ^ 0x80000000u) : __uint_as_float(~mk)) - 1.0f;
  float c = simw[(size_t)row * II + i];
  bool real = x[((size_t)row * II + i) * 8] != PAD_TOK;
  float s = real ? c : neg;
  __shared__ float sv[64];
  sv[i] = s;
  __syncthreads();
  int rank = 0;
  for (int j = 0; j < 64; ++j) {
    float o = sv[j];
    rank += (o > s) || (o == s && j < i);
  }
  bool sel = rank < KK;
  unsigned long long mask = __ballot(sel);
  if (sel) {
    int pos = __popcll(mask & ((1ull << i) - 1ull));
    topidx[row * KK + pos] = i;
  }
}

__global__ __launch_bounds__(128) void k_xself(const int* __restrict__ x,
                                               const int* __restrict__ self_loc,
                                               const float* __restrict__ emb,
                                               float* __restrict__ xself,
                                               __bf16* __restrict__ xself_bf) {
  int b = blockIdx.x, d = threadIdx.x;
  const int* xr = x + ((size_t)(b * SS) * II + self_loc[b]) * 8;
  float acc = 0.f;
#pragma unroll
  for (int jj = 0; jj < 6; ++jj) acc += emb[(size_t)xr[jj] * DD + d];
  xself[b * DD + d] = acc;
  xself_bf[b * DD + d] = (__bf16)acc;
}

__global__ __launch_bounds__(128) void k_build_cont(const int* __restrict__ xc,
                                                    const float* __restrict__ emb,
                                                    __hip_bfloat16* __restrict__ ec,
                                                    float* __restrict__ dtc) {
  int p = blockIdx.x, t = blockIdx.y, d = threadIdx.x;
  const int* xr = xc + ((size_t)p * 128 + t) * 8;
  float acc = 0.f;
#pragma unroll
  for (int jj = 0; jj < 6; ++jj) acc += emb[(size_t)xr[jj] * DD + d];
  ec[((size_t)p * 128 + t) * DD + d] = __float2bfloat16(acc);
  if (d == 0) dtc[p * 128 + t] = (t > 0) ? ((float)xr[6] - (float)xr[-2]) : 0.f;
}

// ------------------------------------------------- weight fragment packing
__global__ __launch_bounds__(64) void k_pack(const float* __restrict__ B,
                                             __bf16* __restrict__ out) {
  int kt = blockIdx.x, tile = blockIdx.y, lane = threadIdx.x;
  const float* src = B + (size_t)(kt * 32 + (lane >> 4) * 8) * 768 + tile * 16 + (lane & 15);
  __bf16* o = out + (((size_t)(kt * 48 + tile) * 64 + lane) * 8);
#pragma unroll
  for (int i = 0; i < 8; ++i) o[i] = (__bf16)src[(size_t)i * 768];
}

// U_c -> fp8 fragments (x8 scale)
__global__ __launch_bounds__(64) void k_pack8(const float* __restrict__ B,
                                              unsigned char* __restrict__ out) {
  int kt = blockIdx.x, tile = blockIdx.y, lane = threadIdx.x;
  const float* src = B + (size_t)(kt * 32 + (lane >> 4) * 8) * 768 + tile * 16 + (lane & 15);
  unsigned char* o = out + (((size_t)(kt * 48 + tile) * 64 + lane) * 8);
#pragma unroll
  for (int i = 0; i < 8; ++i) o[i] = f2fp8(src[(size_t)i * 768] * 8.f);
}

// general pack for [K x N] f32 -> MFMA fragments
__global__ __launch_bounds__(64) void k_packN(const float* __restrict__ B,
                                              __bf16* __restrict__ out, int N) {
  int kt = blockIdx.x, tile = blockIdx.y, lane = threadIdx.x;
  const float* src = B + (size_t)(kt * 32 + (lane >> 4) * 8) * N + tile * 16 + (lane & 15);
  __bf16* o = out + (((size_t)kt * gridDim.y + tile) * 64 + lane) * 8;
#pragma unroll
  for (int i = 0; i < 8; ++i) o[i] = (__bf16)src[(size_t)i * N];
}

// -------- cont-RNN g precompute: G2 (fragment-packed) = ec@Wc + b
__global__ __launch_bounds__(512) void k_gemm_g(const __hip_bfloat16* __restrict__ A,
                                                const __bf16* __restrict__ pB,
                                                const float* __restrict__ bias,
                                                __bf16* __restrict__ G2) {
  const int wv = threadIdx.x >> 6, lane = threadIdx.x & 63;
  const int lr = lane & 15, lg = lane >> 4;
  const int r0 = blockIdx.x * 32;
  f32x4 z4 = {0.f, 0.f, 0.f, 0.f};
  f32x4 acc[2][6];
#pragma unroll
  for (int mt = 0; mt < 2; ++mt)
#pragma unroll
    for (int n = 0; n < 6; ++n) acc[mt][n] = z4;
#pragma unroll
  for (int kt = 0; kt < 4; ++kt) {
    bf16x8 a[2];
#pragma unroll
    for (int mt = 0; mt < 2; ++mt)
      a[mt] = *(const bf16x8*)(A + (size_t)(r0 + mt * 16 + lr) * 128 + kt * 32 + lg * 8);
#pragma unroll
    for (int n = 0; n < 6; ++n) {
      bf16x8 b = *(const bf16x8*)(pB + (((size_t)kt * 48 + wv * 6 + n) * 64 + lane) * 8);
      acc[0][n] = MFMA16(a[0], b, acc[0][n], 0, 0, 0);
      acc[1][n] = MFMA16(a[1], b, acc[1][n], 0, 0, 0);
    }
  }
#pragma unroll
  for (int mt = 0; mt < 2; ++mt)
#pragma unroll
    for (int n = 0; n < 6; ++n) {
      int col = wv * 96 + n * 16 + lr;
      int gate = col >> 8, wvc = (col >> 5) & 7, nt = (col >> 4) & 1;
      float bc = bias[col];
#pragma unroll
      for (int r = 0; r < 4; ++r) {
        int row = r0 + mt * 16 + lg * 4 + r;
        G2[(size_t)row * 1024 + wvc * 128 + lr * 8 + gate * 2 + nt] = (__bf16)(acc[mt][n][r] + bc);
      }
    }
}

// ------------------------------------------------------ fused RNN kernel
__device__ void cont_body(char* smem, const __bf16* __restrict__ G2,
                          const float* __restrict__ dtc,
                          const unsigned char* __restrict__ pU8,
                          const float* __restrict__ wt, float* __restrict__ hcont,
                          int blk) {
  unsigned char(*hbuf)[16 * 256] = (unsigned char(*)[16 * 256])smem;  // 8 KB
  unsigned char(*uL)[30 * 512] = (unsigned char(*)[30 * 512])(smem + 8192);  // 120 KB
  float* dl = (float*)(smem + 8192 + 122880);                                // 8 KB
  const int wv = threadIdx.x >> 6, lane = threadIdx.x & 63;
  const int lr = lane & 15, lg = lane >> 4;
  const int p0 = blk * 16;
  for (int idx = threadIdx.x; idx < 2048; idx += 512)
    dl[idx] = dtc[(p0 + (idx >> 7)) * 128 + (idx & 127)];
  // stage kt3-7 fragments into LDS
  for (int i = threadIdx.x; i < 8 * 30 * 64; i += 512) {
    int l = i & 63;
    int fw = i >> 6;
    int f = fw % 30;
    int w = fw / 30;
    int kt = 3 + f / 6;
    int gi = f % 6;
    *(uint2*)&uL[w][(size_t)f * 512 + l * 8] =
        *(const uint2*)(pU8 + (((size_t)kt * 48 + (gi >> 1) * 16 + w * 2 + (gi & 1)) * 64 + l) * 8);
  }
  // kt0-2 fragments persistent in VGPRs (36 regs)
  long fr[3][6];
#pragma unroll
  for (int kt = 0; kt < 3; ++kt)
#pragma unroll
    for (int gi = 0; gi < 6; ++gi)
      fr[kt][gi] =
          *(const long*)(pU8 + (((size_t)kt * 48 + (gi >> 1) * 16 + wv * 2 + (gi & 1)) * 64 + lane) * 8);

  float wtv[2];
#pragma unroll
  for (int nt = 0; nt < 2; ++nt) wtv[nt] = wt[wv * 32 + nt * 16 + lr];
  float h[2][4];
#pragma unroll
  for (int nt = 0; nt < 2; ++nt)
#pragma unroll
    for (int r = 0; r < 4; ++r) h[nt][r] = 0.f;

  const uint4* G2v = (const uint4*)G2;
  const size_t gb0 = (size_t)(p0 + lg * 4) * 16384 + wv * 16 + lr;
  __syncthreads();

  for (int t = 0; t < 128; ++t) {
    unsigned char* hb = hbuf[t & 1];
    uint4 Gv[4];
#pragma unroll
    for (int r = 0; r < 4; ++r) Gv[r] = G2v[gb0 + (size_t)r * 16384 + (size_t)t * 128];
    float hd[2][4];
#pragma unroll
    for (int r = 0; r < 4; ++r) {
      float dtv = dl[(lg * 4 + r) * 128 + t];
#pragma unroll
      for (int nt = 0; nt < 2; ++nt) hd[nt][r] = h[nt][r] * __expf(-fmaxf(dtv * wtv[nt], 0.f));
    }
    const int c0 = wv * 32 + lr, c1 = wv * 32 + 16 + lr;
#pragma unroll
    for (int r = 0; r < 4; ++r) {
      int row = lg * 4 + r;
      int sw = (row & 15) << 3;
      unsigned pk = cvt2fp8(hd[0][r] * 16.f, hd[1][r] * 16.f);
      hb[row * 256 + (c0 ^ sw)] = (unsigned char)pk;
      hb[row * 256 + (c1 ^ sw)] = (unsigned char)(pk >> 8);
    }
    __syncthreads();
    f32x4 acc[3][2];
#pragma unroll
    for (int g = 0; g < 3; ++g)
#pragma unroll
      for (int nt = 0; nt < 2; ++nt) acc[g][nt] = f32x4{0.f, 0.f, 0.f, 0.f};
#pragma unroll
    for (int kt = 0; kt < 8; ++kt) {
      long a = *(const long*)&hb[lr * 256 + ((kt * 32 + lg * 8) ^ ((lr & 15) << 3))];
#pragma unroll
      for (int gi = 0; gi < 6; ++gi) {
        long b = (kt < 3) ? fr[kt][gi]
                          : *(const long*)&uL[wv][(size_t)((kt - 3) * 6 + gi) * 512 + lane * 8];
        acc[gi >> 1][gi & 1] = MFMA8(a, b, acc[gi >> 1][gi & 1], 0, 0, 0);
      }
    }
#pragma unroll
    for (int nt = 0; nt < 2; ++nt)
#pragma unroll
      for (int r = 0; r < 4; ++r) {
        unsigned uz = nt ? (Gv[r].x >> 16) : (Gv[r].x & 0xffffu);
        unsigned ur = nt ? (Gv[r].y >> 16) : (Gv[r].y & 0xffffu);
        unsigned un = nt ? (Gv[r].z >> 16) : (Gv[r].z & 0xffffu);
        const float us = 0.0078125f;  // 1/(16*8)
        float zz = sigm(bfu(uz) + acc[0][nt][r] * us);
        float rr = sigm(bfu(ur) + acc[1][nt][r] * us);
        float nn = tanh_fast(bfu(un) + rr * acc[2][nt][r] * us);
        float hnew = (1.f - zz) * hd[nt][r] + zz * nn;
        h[nt][r] = hnew;
        if (t >= 124)
          hcont[((size_t)(p0 + lg * 4 + r) * 4 + (t - 124)) * 256 + wv * 32 + nt * 16 + lr] = hnew;
      }
  }
}

__device__ void main_body(char* smem, const int* __restrict__ x,
                          const int* __restrict__ self_loc,
                          const float* __restrict__ emb,
                          const int* __restrict__ topidx,
                          const __bf16* __restrict__ xself_bf,
                          const __bf16* __restrict__ pWs, const __bf16* __restrict__ pWe,
                          const float* __restrict__ gbias, __bf16* __restrict__ Gm2,
                          const __bf16* __restrict__ pU, const float* __restrict__ wt,
                          float* __restrict__ hmain, int blk) {
  __bf16(*hbuf)[32 * 256] = (__bf16(*)[32 * 256])smem;  // 2 x 16KB
  __bf16* el = (__bf16*)smem;                           // phase-1 tile (8KB, overlaps)
  float* dl = (float*)(smem + 32768);                   // KK*32 floats
  const int wv = threadIdx.x >> 6, lane = threadIdx.x & 63;
  const int lr = lane & 15, lg = lane >> 4;
  const int n0 = blk * 32;
  f32x4 z4 = {0.f, 0.f, 0.f, 0.f};
  const uint4* Gv4 = (const uint4*)Gm2;

  // ---------------- phase 1: build the 15 input-gate tiles ----------------
  for (int t = 0; t < KK; ++t) {
    {
      int rr = threadIdx.x >> 5, q = threadIdx.x & 31;
#pragma unroll
      for (int pass = 0; pass < 2; ++pass) {
        int rloc = pass * 16 + rr;
        int n = n0 + rloc;
        int b = n >> 4, s = n & 15;
        bool ovr = (s == 0) && (t == KK - 1);
        int item = ovr ? self_loc[b] : topidx[n * KK + t];
        const int* xr = x + ((size_t)n * II + item) * 8;
        float4 a4 = {0.f, 0.f, 0.f, 0.f};
#pragma unroll
        for (int jj = 0; jj < 6; ++jj) {
          float4 v = *(const float4*)(emb + (size_t)xr[jj] * DD + q * 4);
          a4.x += v.x;
          a4.y += v.y;
          a4.z += v.z;
          a4.w += v.w;
        }
        bf16x4 ov = {(__bf16)a4.x, (__bf16)a4.y, (__bf16)a4.z, (__bf16)a4.w};
        *(bf16x4*)&el[(rloc * 128 + q * 4) ^ ((rloc & 7) << 3)] = ov;
        if (q == 0) {
          float dtv = 0.f;
          if (t > 0) {
            int pitem = topidx[n * KK + t - 1];
            dtv = (float)xr[6] - (float)x[((size_t)n * II + pitem) * 8 + 6];
          }
          dl[t * 32 + rloc] = dtv;
        }
      }
    }
    __syncthreads();
    f32x4 acc[3][2][2];
#pragma unroll
    for (int g = 0; g < 3; ++g)
#pragma unroll
      for (int mt = 0; mt < 2; ++mt)
#pragma unroll
        for (int nt = 0; nt < 2; ++nt) acc[g][mt][nt] = z4;
#pragma unroll
    for (int kt = 0; kt < 8; ++kt) {
      bf16x8 a[2];
#pragma unroll
      for (int mt = 0; mt < 2; ++mt) {
        if (kt < 4)
          a[mt] = *(const bf16x8*)(xself_bf + (size_t)((n0 + mt * 16) >> 4) * 128 + kt * 32 + lg * 8);
        else {
          int row = mt * 16 + lr;
          a[mt] = *(const bf16x8*)&el[(row * 128 + (kt - 4) * 32 + lg * 8) ^ ((row & 7) << 3)];
        }
      }
      const __bf16* pB = (kt < 4) ? (pWs + (size_t)kt * 48 * 512) : (pWe + (size_t)(kt - 4) * 48 * 512);
#pragma unroll
      for (int g = 0; g < 3; ++g)
#pragma unroll
        for (int nt = 0; nt < 2; ++nt) {
          bf16x8 b = *(const bf16x8*)(pB + (((size_t)g * 16 + wv * 2 + nt) * 64 + lane) * 8);
#pragma unroll
          for (int mt = 0; mt < 2; ++mt) acc[g][mt][nt] = MFMA16(a[mt], b, acc[g][mt][nt], 0, 0, 0);
        }
    }
#pragma unroll
    for (int mt = 0; mt < 2; ++mt)
#pragma unroll
      for (int g = 0; g < 3; ++g)
#pragma unroll
        for (int nt = 0; nt < 2; ++nt) {
          int col = g * 256 + wv * 32 + nt * 16 + lr;
          float bc = gbias[col];
#pragma unroll
          for (int r = 0; r < 4; ++r) {
            size_t rf = (size_t)t * 8192 + n0 + mt * 16 + lg * 4 + r;
            Gm2[rf * 1024 + wv * 128 + lr * 8 + g * 2 + nt] = (__bf16)(acc[g][mt][nt][r] + bc);
          }
        }
    __syncthreads();
  }

  // ---------------- phase 2: recurrence ----------------
  float wtv[2];
#pragma unroll
  for (int nt = 0; nt < 2; ++nt) wtv[nt] = wt[wv * 32 + nt * 16 + lr];
  float h[2][2][4];
#pragma unroll
  for (int mt = 0; mt < 2; ++mt)
#pragma unroll
    for (int nt = 0; nt < 2; ++nt)
#pragma unroll
      for (int r = 0; r < 4; ++r) h[mt][nt][r] = 0.f;

  for (int t = 0; t < KK; ++t) {
    __bf16* hb = hbuf[t & 1];
#pragma unroll
    for (int mt = 0; mt < 2; ++mt)
#pragma unroll
      for (int r = 0; r < 4; ++r) {
        float dtv = dl[t * 32 + mt * 16 + lg * 4 + r];
        int row = mt * 16 + lg * 4 + r;
#pragma unroll
        for (int nt = 0; nt < 2; ++nt) {
          float hdv = h[mt][nt][r] * __expf(-fmaxf(dtv * wtv[nt], 0.f));
          hb[((row * 256) + (wv * 32 + nt * 16 + lr)) ^ ((row & 7) << 3)] = (__bf16)hdv;
        }
      }
    __syncthreads();
    f32x4 acc[3][2][2];
#pragma unroll
    for (int g = 0; g < 3; ++g)
#pragma unroll
      for (int mt = 0; mt < 2; ++mt)
#pragma unroll
        for (int nt = 0; nt < 2; ++nt) acc[g][mt][nt] = z4;
#pragma unroll 2
    for (int kt = 0; kt < 8; ++kt) {
      bf16x8 a[2];
#pragma unroll
      for (int mt = 0; mt < 2; ++mt) {
        int row = mt * 16 + lr;
        int s = ((row * 256) + (kt * 32 + lg * 8)) ^ ((row & 7) << 3);
        a[mt] = *(const bf16x8*)&hb[s];
      }
#pragma unroll
      for (int g = 0; g < 3; ++g)
#pragma unroll
        for (int nt = 0; nt < 2; ++nt) {
          bf16x8 b = *(const bf16x8*)(pU + (((size_t)kt * 48 + g * 16 + wv * 2 + nt) * 64 + lane) * 8);
#pragma unroll
          for (int mt = 0; mt < 2; ++mt) acc[g][mt][nt] = MFMA16(a[mt], b, acc[g][mt][nt], 0, 0, 0);
        }
    }
    // G loads issued after u-GEMM (short liveness)
    uint4 Gv[2][4];
#pragma unroll
    for (int mt = 0; mt < 2; ++mt)
#pragma unroll
      for (int r = 0; r < 4; ++r)
        Gv[mt][r] = Gv4[((size_t)t * 8192 + n0 + mt * 16 + lg * 4 + r) * 128 + wv * 16 + lr];
#pragma unroll
    for (int mt = 0; mt < 2; ++mt)
#pragma unroll
      for (int r = 0; r < 4; ++r) {
        float dtv = dl[t * 32 + mt * 16 + lg * 4 + r];
#pragma unroll
        for (int nt = 0; nt < 2; ++nt) {
          unsigned uz = nt ? (Gv[mt][r].x >> 16) : (Gv[mt][r].x & 0xffffu);
          unsigned ur = nt ? (Gv[mt][r].y >> 16) : (Gv[mt][r].y & 0xffffu);
          unsigned un = nt ? (Gv[mt][r].z >> 16) : (Gv[mt][r].z & 0xffffu);
          float hdv = h[mt][nt][r] * __expf(-fmaxf(dtv * wtv[nt], 0.f));
          float zz = sigm(bfu(uz) + acc[0][mt][nt][r]);
          float rr = sigm(bfu(ur) + acc[1][mt][nt][r]);
          float nn = tanh_fast(bfu(un) + rr * acc[2][mt][nt][r]);
          h[mt][nt][r] = (1.f - zz) * hdv + zz * nn;
        }
      }
  }
  __syncthreads();
#pragma unroll
  for (int mt = 0; mt < 2; ++mt)
#pragma unroll
    for (int nt = 0; nt < 2; ++nt)
#pragma unroll
      for (int r = 0; r < 4; ++r)
        hmain[(size_t)(n0 + mt * 16 + lg * 4 + r) * 256 + wv * 32 + nt * 16 + lr] = h[mt][nt][r];
}

__global__ __launch_bounds__(512) void k_rnn_fused(
    const __bf16* __restrict__ G2, const float* __restrict__ dtc,
    const unsigned char* __restrict__ pU8, const float* __restrict__ wt_c,
    float* __restrict__ hcont, const int* __restrict__ x,
    const int* __restrict__ self_loc, const float* __restrict__ emb,
    const int* __restrict__ topidx, const __bf16* __restrict__ xself_bf,
    const __bf16* __restrict__ pWs, const __bf16* __restrict__ pWe,
    const float* __restrict__ b_rnn, __bf16* __restrict__ Gm2,
    const __bf16* __restrict__ pU, const float* __restrict__ wt_m,
    float* __restrict__ hmain) {
  __shared__ __align__(16) char smem[8192 + 122880 + 8192];  // 139 KB union
  if (blockIdx.x < 8)
    cont_body(smem, G2, dtc, pU8, wt_c, hcont, blockIdx.x);
  else
    main_body(smem, x, self_loc, emb, topidx, xself_bf, pWs, pWe, b_rnn, Gm2, pU, wt_m,
              hmain, blockIdx.x - 8);
}

// ------------------------------------------------------------------ tail
__global__ __launch_bounds__(256) void k_att(const float* __restrict__ hmain,
                                             const float* __restrict__ xself,
                                             const float* __restrict__ hc,
                                             const float* __restrict__ Wv,
                                             const float* __restrict__ bv,
                                             float* __restrict__ hh,
                                             __bf16* __restrict__ hh_bf) {
  int b = blockIdx.x, tid = threadIdx.x;
  __shared__ float hl[16 * 256];
  __shared__ float aa[16 * 4];
  for (int idx = tid; idx < 4096; idx += 256) hl[idx] = hmain[(size_t)b * SS * HH + idx];
  __syncthreads();
  if (tid < 64) {
    int s = tid >> 2, m = tid & 3;
    float acc = bv[m];
    for (int j = 0; j < 256; ++j)
      acc += hl[s * 256 + j] * Wv[j * 4 + m] + hl[j] * Wv[(256 + j) * 4 + m];
    aa[s * 4 + m] = tanh_fast(acc);
  }
  __syncthreads();
  if (tid < 4) {
    int m = tid;
    float mx = -1e30f;
    for (int s = 0; s < 16; ++s) mx = fmaxf(mx, aa[s * 4 + m]);
    float sum = 0.f;
    for (int s = 0; s < 16; ++s) sum += __expf(aa[s * 4 + m] - mx);
    float inv = 1.f / sum;
    for (int s = 0; s < 16; ++s) aa[s * 4 + m] = __expf(aa[s * 4 + m] - mx) * inv;
  }
  __syncthreads();
  float a0 = 0.f, a1 = 0.f, a2 = 0.f, a3 = 0.f;
  for (int s = 0; s < 16; ++s) {
    float hv = hl[s * 256 + tid];
    a0 = fmaf(aa[s * 4 + 0], hv, a0);
    a1 = fmaf(aa[s * 4 + 1], hv, a1);
    a2 = fmaf(aa[s * 4 + 2], hv, a2);
    a3 = fmaf(aa[s * 4 + 3], hv, a3);
  }
  float* hb = hh + (size_t)b * 1664;
  __bf16* hf = hh_bf + (size_t)b * 1664;
  hb[384 + 0 * 256 + tid] = a0;
  hb[384 + 1 * 256 + tid] = a1;
  hb[384 + 2 * 256 + tid] = a2;
  hb[384 + 3 * 256 + tid] = a3;
  hf[384 + 0 * 256 + tid] = (__bf16)a0;
  hf[384 + 1 * 256 + tid] = (__bf16)a1;
  hf[384 + 2 * 256 + tid] = (__bf16)a2;
  hf[384 + 3 * 256 + tid] = (__bf16)a3;
  if (tid < 128) {
    hb[tid] = xself[b * DD + tid];
    hf[tid] = (__bf16)xself[b * DD + tid];
  }
  hb[128 + tid] = hl[tid];
  hf[128 + tid] = (__bf16)hl[tid];
  float hcv = hc[(size_t)b * HH + tid];
  hb[1408 + tid] = hcv;
  hf[1408 + tid] = (__bf16)hcv;
}

// MFMA MLP layer: C = leakyrelu(A @ W + b)
__global__ __launch_bounds__(512) void k_mlp_mfma(const __bf16* __restrict__ A,
                                                  const __bf16* __restrict__ pW,
                                                  const float* __restrict__ bias,
                                                  __bf16* __restrict__ C, int K, int N) {
  const int wv = threadIdx.x >> 6, lane = threadIdx.x & 63;
  const int lr = lane & 15, lg = lane >> 4;
  const int r0 = blockIdx.y * 32;
  const int c0 = blockIdx.x * 256;
  const int NT = N >> 4;
  const int KT = K >> 5;
  f32x4 acc[2][2];
#pragma unroll
  for (int mt = 0; mt < 2; ++mt)
#pragma unroll
    for (int nt = 0; nt < 2; ++nt) acc[mt][nt] = f32x4{0.f, 0.f, 0.f, 0.f};
  for (int kt = 0; kt < KT; ++kt) {
    bf16x8 a[2];
#pragma unroll
    for (int mt = 0; mt < 2; ++mt)
      a[mt] = *(const bf16x8*)(A + (size_t)(r0 + mt * 16 + lr) * K + kt * 32 + lg * 8);
#pragma unroll
    for (int nt = 0; nt < 2; ++nt) {
      bf16x8 b = *(const bf16x8*)(pW + (((size_t)kt * NT + (c0 >> 4) + wv * 2 + nt) * 64 + lane) * 8);
#pragma unroll
      for (int mt = 0; mt < 2; ++mt) acc[mt][nt] = MFMA16(a[mt], b, acc[mt][nt], 0, 0, 0);
    }
  }
#pragma unroll
  for (int nt = 0; nt < 2; ++nt) {
    int col = c0 + wv * 32 + nt * 16 + lr;
    float bc = bias[col];
#pragma unroll
    for (int mt = 0; mt < 2; ++mt)
#pragma unroll
      for (int r = 0; r < 4; ++r) {
        float v = acc[mt][nt][r] + bc;
        v = v > 0.f ? v : 0.01f * v;
        C[(size_t)(r0 + mt * 16 + lg * 4 + r) * N + col] = (__bf16)v;
      }
  }
}

__global__ __launch_bounds__(64) void k_head(const __bf16* __restrict__ A,
                                             const float* __restrict__ Wp,
                                             const float* __restrict__ bp,
                                             float* __restrict__ out) {
  int row = blockIdx.x, l = threadIdx.x;
  float acc = 0.f;
  for (int j = l; j < 256; j += 64) acc = fmaf((float)A[(size_t)row * 256 + j], Wp[j], acc);
  for (int o = 32; o; o >>= 1) acc += __shfl_xor(acc, o);
  if (l == 0) out[row] = 1.f / (1.f + __expf(-(acc + bp[0])));
}

extern "C" void kernel_launch(void* const* d_in, const int* in_sizes, int n_in,
                              void* d_out, int out_size, void* d_ws, size_t ws_size,
                              hipStream_t stream) {
  const int* x = (const int*)d_in[0];
  const int* xc = (const int*)d_in[1];
  const int* self_loc = (const int*)d_in[2];
  const float* emb = (const float*)d_in[3];
  const float* W_rnn = (const float*)d_in[4];
  const float* U_rnn = (const float*)d_in[5];
  const float* b_rnn = (const float*)d_in[6];
  const float* wt_rnn = (const float*)d_in[7];
  const float* W_c = (const float*)d_in[8];
  const float* U_c = (const float*)d_in[9];
  const float* b_c = (const float*)d_in[10];
  const float* wt_c = (const float*)d_in[11];
  const float* Wv = (const float*)d_in[12];
  const float* bv = (const float*)d_in[13];
  const float* W0 = (const float*)d_in[14];
  const float* b0 = (const float*)d_in[15];
  const float* W1 = (const float*)d_in[16];
  const float* b1 = (const float*)d_in[17];
  const float* W2 = (const float*)d_in[18];
  const float* b2 = (const float*)d_in[19];
  const float* Wp = (const float*)d_in[20];
  const float* bp = (const float*)d_in[21];
  float* out = (float*)d_out;

  char* ws = (char*)d_ws;
  size_t cur = 0;
  auto alloc = [&](size_t bytes) {
    char* p = ws + cur;
    cur += (bytes + 255) & ~(size_t)255;
    return p;
  };
  float* es = (float*)alloc((size_t)BB * DD * 4);
  float* ns = (float*)alloc(BB * 4);
  unsigned* minu = (unsigned*)alloc(4);
  float* simw = (float*)alloc((size_t)BB * SS * II * 4);
  int* topidx = (int*)alloc((size_t)BB * SS * KK * 4);
  float* xself = (float*)alloc((size_t)BB * DD * 4);
  __bf16* xself_bf = (__bf16*)alloc((size_t)BB * DD * 2);
  float* dtc = (float*)alloc((size_t)128 * 128 * 4);
  float* hcont = (float*)alloc((size_t)BB * HH * 4);
  float* hh = (float*)alloc((size_t)BB * 1664 * 4);
  __bf16* hh_bf = (__bf16*)alloc((size_t)BB * 1664 * 2);
  __bf16* z0 = (__bf16*)alloc((size_t)BB * 1024 * 2);
  __bf16* z1 = (__bf16*)alloc((size_t)BB * 512 * 2);
  __bf16* z2 = (__bf16*)alloc((size_t)BB * 256 * 2);
  float* hmain = (float*)alloc((size_t)8192 * HH * 4);
  __hip_bfloat16* ec = (__hip_bfloat16*)alloc((size_t)16384 * DD * 2);
  __bf16* G2 = (__bf16*)alloc((size_t)16384 * 1024 * 2);
  __bf16* Gm2 = (__bf16*)alloc((size_t)KK * 8192 * 1024 * 2);
  __bf16* pWs = (__bf16*)alloc((size_t)4 * 48 * 64 * 8 * 2);
  __bf16* pWe = (__bf16*)alloc((size_t)4 * 48 * 64 * 8 * 2);
  __bf16* pU = (__bf16*)alloc((size_t)8 * 48 * 64 * 8 * 2);
  __bf16* pWc = (__bf16*)alloc((size_t)4 * 48 * 64 * 8 * 2);
  unsigned char* pU8 = (unsigned char*)alloc((size_t)8 * 48 * 64 * 8);
  __bf16* pW0 = (__bf16*)alloc((size_t)52 * 64 * 64 * 8 * 2);
  __bf16* pW1 = (__bf16*)alloc((size_t)32 * 32 * 64 * 8 * 2);
  __bf16* pW2 = (__bf16*)alloc((size_t)16 * 16 * 64 * 8 * 2);
  (void)ws_size;

  hipLaunchKernelGGL(k_init, dim3(1), dim3(1), 0, stream, minu);
  hipLaunchKernelGGL(k_eself, dim3(BB), dim3(128), 0, stream, x, self_loc, emb, es, ns);
  hipLaunchKernelGGL(k_cos, dim3(BB * SS), dim3(256), 0, stream, x, emb, es, ns, simw, minu);
  hipLaunchKernelGGL(k_topk, dim3(BB * SS), dim3(64), 0, stream, x, simw, minu, topidx);
  hipLaunchKernelGGL(k_xself, dim3(BB), dim3(128), 0, stream, x, self_loc, emb, xself,
                     xself_bf);
  hipLaunchKernelGGL(k_build_cont, dim3(128, 128), dim3(128), 0, stream, xc, emb, ec, dtc);
  hipLaunchKernelGGL(k_pack, dim3(4, 48), dim3(64), 0, stream, W_rnn, pWs);
  hipLaunchKernelGGL(k_pack, dim3(4, 48), dim3(64), 0, stream, W_rnn + 128 * 768, pWe);
  hipLaunchKernelGGL(k_pack, dim3(8, 48), dim3(64), 0, stream, U_rnn, pU);
  hipLaunchKernelGGL(k_pack, dim3(4, 48), dim3(64), 0, stream, W_c, pWc);
  hipLaunchKernelGGL(k_pack8, dim3(8, 48), dim3(64), 0, stream, U_c, pU8);
  hipLaunchKernelGGL(k_packN, dim3(52, 64), dim3(64), 0, stream, W0, pW0, 1024);
  hipLaunchKernelGGL(k_packN, dim3(32, 32), dim3(64), 0, stream, W1, pW1, 512);
  hipLaunchKernelGGL(k_packN, dim3(16, 16), dim3(64), 0, stream, W2, pW2, 256);
  hipLaunchKernelGGL(k_gemm_g, dim3(512), dim3(512), 0, stream, ec, pWc, b_c, G2);
  hipLaunchKernelGGL(k_rnn_fused, dim3(264), dim3(512), 0, stream, G2, dtc, pU8, wt_c,
                     hcont, x, self_loc, emb, topidx, xself_bf, pWs, pWe, b_rnn, Gm2, pU,
                     wt_rnn, hmain);
  hipLaunchKernelGGL(k_att, dim3(BB), dim3(256), 0, stream, hmain, xself, hcont, Wv, bv, hh,
                     hh_bf);
  hipLaunchKernelGGL(k_mlp_mfma, dim3(4, 16), dim3(512), 0, stream, hh_bf, pW0, b0, z0,
                     1664, 1024);
  hipLaunchKernelGGL(k_mlp_mfma, dim3(2, 16), dim3(512), 0, stream, z0, pW1, b1, z1, 1024,
                     512);
  hipLaunchKernelGGL(k_mlp_mfma, dim3(1, 16), dim3(512), 0, stream, z1, pW2, b2, z2, 512,
                     256);
  hipLaunchKernelGGL(k_head, dim3(BB), dim3(64), 0, stream, z2, Wp, bp, out);
}

// Round 17
// 774.385 us; speedup vs baseline: 1.2909x; 1.2909x over previous
//
#include <hip/hip_runtime.h>
#include <hip/hip_bf16.h>

// SearchPredictModel round 17:
//  - Gm2 precompute ELIMINATED. Main recurrence computes e-GEMM (from 30MB
//    em buffer, R8 design) + u-GEMM in-loop, nt-SPLIT into two passes so
//    per-pass acc = 32 regs (no Gv, no spill). b_rnn biases applied at gates.
//  - k_build_main restored (R5 vectorized gather -> em + dtm + xself).
//  - cont path unchanged (fp8-resident U, R13/R14-proven).

#define PAD_TOK 200000
#define DD 128
#define HH 256
#define KK 15
#define BB 512
#define SS 16
#define II 64

typedef __bf16 bf16x8 __attribute__((ext_vector_type(8)));
typedef __bf16 bf16x4 __attribute__((ext_vector_type(4)));
typedef float f32x4 __attribute__((ext_vector_type(4)));
#define MFMA16 __builtin_amdgcn_mfma_f32_16x16x32_bf16
#define MFMA8 __builtin_amdgcn_mfma_f32_16x16x32_fp8_fp8

__device__ __forceinline__ float sigm(float x) { return 1.f / (1.f + __expf(-x)); }
__device__ __forceinline__ float tanh_fast(float x) {
  x = fminf(fmaxf(x, -15.f), 15.f);
  float e2 = __expf(2.f * x);
  return (e2 - 1.f) / (e2 + 1.f);
}
__device__ __forceinline__ float bfu(unsigned u16) { return __uint_as_float(u16 << 16); }

// float -> fp8 e4m3 (OCP), RNE, FTZ below 2^-6 (software fallback)
__device__ __forceinline__ unsigned char f2fp8(float x) {
  unsigned u = __float_as_uint(x);
  unsigned s = (u >> 31) << 7;
  int e = (int)((u >> 23) & 0xff) - 127;
  if (e < -6) return (unsigned char)s;
  unsigned m = (u >> 20) & 7;
  unsigned rest = u & 0xFFFFF;
  if (rest > 0x80000 || (rest == 0x80000 && (m & 1))) {
    ++m;
    if (m == 8) {
      m = 0;
      ++e;
    }
  }
  if (e > 7) {
    e = 7;
    m = 6;
  }
  return (unsigned char)(s | ((unsigned)(e + 7) << 3) | m);
}

__device__ __forceinline__ unsigned cvt2fp8(float a, float b) {
#if __has_builtin(__builtin_amdgcn_cvt_pk_fp8_f32)
  return (unsigned)__builtin_amdgcn_cvt_pk_fp8_f32(a, b, 0, false) & 0xffffu;
#else
  return (unsigned)f2fp8(a) | ((unsigned)f2fp8(b) << 8);
#endif
}

// ---------------------------------------------------------------- front end
__global__ __launch_bounds__(128) void k_eself(const int* __restrict__ x,
                                               const int* __restrict__ self_loc,
                                               const float* __restrict__ emb,
                                               float* __restrict__ es,
                                               float* __restrict__ ns) {
  int b = blockIdx.x, d = threadIdx.x;
  int tok = x[((size_t)(b * SS + 0) * II + self_loc[b]) * 8 + 5];
  float v = emb[(size_t)tok * DD + d];
  es[b * DD + d] = v;
  __shared__ float red[128];
  red[d] = v * v;
  __syncthreads();
  for (int o = 64; o > 0; o >>= 1) {
    if (d < o) red[d] += red[d + o];
    __syncthreads();
  }
  if (d == 0) ns[b] = fmaxf(sqrtf(red[0]), 1e-8f);
}

__global__ void k_init(unsigned* minu) { *minu = 0xFFFFFFFFu; }

// one block per row (b,s); 64 items x 4 lanes each
__global__ __launch_bounds__(256) void k_cos(const int* __restrict__ x,
                                             const float* __restrict__ emb,
                                             const float* __restrict__ es,
                                             const float* __restrict__ ns,
                                             float* __restrict__ simw,
                                             unsigned* __restrict__ minu) {
  int row = blockIdx.x;
  int b = row >> 4;
  int tid = threadIdx.x;
  int i = tid >> 2;  // item
  int q = tid & 3;   // dim quarter (32 dims)
  __shared__ float esl[128];
  __shared__ unsigned smin[64];
  if (tid < 128) esl[tid] = es[b * DD + tid];
  __syncthreads();
  const int* xr = x + ((size_t)row * II + i) * 8;
  int tok = xr[5];
  int first = xr[0];
  const float4* ep = (const float4*)(emb + (size_t)tok * DD + q * 32);
  const float4* sp = (const float4*)(esl + q * 32);
  float dot = 0.f, ss = 0.f;
#pragma unroll
  for (int j = 0; j < 8; ++j) {
    float4 a = ep[j];
    float4 e = sp[j];
    dot += a.x * e.x + a.y * e.y + a.z * e.z + a.w * e.w;
    ss += a.x * a.x + a.y * a.y + a.z * a.z + a.w * a.w;
  }
  dot += __shfl_xor(dot, 1);
  ss += __shfl_xor(ss, 1);
  dot += __shfl_xor(dot, 2);
  ss += __shfl_xor(ss, 2);
  if (q == 0) {
    float cosv = dot / (fmaxf(sqrtf(ss), 1e-8f) * ns[b]);
    simw[(size_t)row * II + i] = cosv;
    unsigned key = 0xFFFFFFFFu;
    if (first != PAD_TOK) {
      unsigned u = __float_as_uint(cosv);
      key = (cosv < 0.f) ? ~u : (u | 0x80000000u);
    }
    smin[i] = key;
  }
  __syncthreads();
  if (tid < 64) {
    unsigned m = smin[tid];
    for (int o = 32; o; o >>= 1) m = min(m, __shfl_xor(m, o));
    if (tid == 0 && m != 0xFFFFFFFFu) atomicMin(minu, m);
  }
}

__global__ __launch_bounds__(64) void k_topk(const int* __restrict__ x,
                                             const float* __restrict__ simw,
                                             const unsigned* __restrict__ minu,
                                             int* __restrict__ topidx) {
  int row = blockIdx.x, i = threadIdx.x;
  unsigned mk = *minu;
  float neg = ((mk & 0x80000000u) ? __uint_as_float(mk ^ 0x80000000u) : __uint_as_float(~mk)) - 1.0f;
  float c = simw[(size_t)row * II + i];
  bool real = x[((size_t)row * II + i) * 8] != PAD_TOK;
  float s = real ? c : neg;
  __shared__ float sv[64];
  sv[i] = s;
  __syncthreads();
  int rank = 0;
  for (int j = 0; j < 64; ++j) {
    float o = sv[j];
    rank += (o > s) || (o == s && j < i);
  }
  bool sel = rank < KK;
  unsigned long long mask = __ballot(sel);
  if (sel) {
    int pos = __popcll(mask & ((1ull << i) - 1ull));
    topidx[row * KK + pos] = i;
  }
}

// 8 items/block x 32 lanes (float4 per lane) -> em (bf16), dtm, xself
__global__ __launch_bounds__(256) void k_build_main(const int* __restrict__ x,
                                                    const int* __restrict__ self_loc,
                                                    const float* __restrict__ emb,
                                                    const int* __restrict__ topidx,
                                                    __bf16* __restrict__ em,
                                                    float* __restrict__ dtm,
                                                    float* __restrict__ xself,
                                                    __bf16* __restrict__ xself_bf) {
  int t = blockIdx.y;
  int n = blockIdx.x * 8 + (threadIdx.x >> 5);
  int q = threadIdx.x & 31;
  int b = n >> 4, s = n & 15;
  bool ovr = (s == 0) && (t == KK - 1);
  int item = ovr ? self_loc[b] : topidx[n * KK + t];
  const int* xr = x + ((size_t)n * II + item) * 8;
  int toks[6];
#pragma unroll
  for (int jj = 0; jj < 6; ++jj) toks[jj] = xr[jj];
  float4 acc = {0.f, 0.f, 0.f, 0.f};
#pragma unroll
  for (int jj = 0; jj < 6; ++jj) {
    float4 v = *(const float4*)(emb + (size_t)toks[jj] * DD + q * 4);
    acc.x += v.x;
    acc.y += v.y;
    acc.z += v.z;
    acc.w += v.w;
  }
  bf16x4 ov = {(__bf16)acc.x, (__bf16)acc.y, (__bf16)acc.z, (__bf16)acc.w};
  *(bf16x4*)(em + ((size_t)t * 8192 + n) * DD + q * 4) = ov;
  if (ovr) {
    *(float4*)(xself + b * DD + q * 4) = acc;
    *(bf16x4*)(xself_bf + b * DD + q * 4) = ov;
  }
  if (q == 0) {
    float dtv = 0.f;
    if (t > 0) {
      int pitem = topidx[n * KK + t - 1];
      dtv = (float)xr[6] - (float)x[((size_t)n * II + pitem) * 8 + 6];
    }
    dtm[t * 8192 + n] = dtv;
  }
}

__global__ __launch_bounds__(128) void k_build_cont(const int* __restrict__ xc,
                                                    const float* __restrict__ emb,
                                                    __hip_bfloat16* __restrict__ ec,
                                                    float* __restrict__ dtc) {
  int p = blockIdx.x, t = blockIdx.y, d = threadIdx.x;
  const int* xr = xc + ((size_t)p * 128 + t) * 8;
  float acc = 0.f;
#pragma unroll
  for (int jj = 0; jj < 6; ++jj) acc += emb[(size_t)xr[jj] * DD + d];
  ec[((size_t)p * 128 + t) * DD + d] = __float2bfloat16(acc);
  if (d == 0) dtc[p * 128 + t] = (t > 0) ? ((float)xr[6] - (float)xr[-2]) : 0.f;
}

// ------------------------------------------------- weight fragment packing
__global__ __launch_bounds__(64) void k_pack(const float* __restrict__ B,
                                             __bf16* __restrict__ out) {
  int kt = blockIdx.x, tile = blockIdx.y, lane = threadIdx.x;
  const float* src = B + (size_t)(kt * 32 + (lane >> 4) * 8) * 768 + tile * 16 + (lane & 15);
  __bf16* o = out + (((size_t)(kt * 48 + tile) * 64 + lane) * 8);
#pragma unroll
  for (int i = 0; i < 8; ++i) o[i] = (__bf16)src[(size_t)i * 768];
}

// U_c -> fp8 fragments (x8 scale)
__global__ __launch_bounds__(64) void k_pack8(const float* __restrict__ B,
                                              unsigned char* __restrict__ out) {
  int kt = blockIdx.x, tile = blockIdx.y, lane = threadIdx.x;
  const float* src = B + (size_t)(kt * 32 + (lane >> 4) * 8) * 768 + tile * 16 + (lane & 15);
  unsigned char* o = out + (((size_t)(kt * 48 + tile) * 64 + lane) * 8);
#pragma unroll
  for (int i = 0; i < 8; ++i) o[i] = f2fp8(src[(size_t)i * 768] * 8.f);
}

// general pack for [K x N] f32 -> MFMA fragments
__global__ __launch_bounds__(64) void k_packN(const float* __restrict__ B,
                                              __bf16* __restrict__ out, int N) {
  int kt = blockIdx.x, tile = blockIdx.y, lane = threadIdx.x;
  const float* src = B + (size_t)(kt * 32 + (lane >> 4) * 8) * N + tile * 16 + (lane & 15);
  __bf16* o = out + (((size_t)kt * gridDim.y + tile) * 64 + lane) * 8;
#pragma unroll
  for (int i = 0; i < 8; ++i) o[i] = (__bf16)src[(size_t)i * N];
}

// -------- cont-RNN g precompute: G2 (fragment-packed) = ec@Wc + b
__global__ __launch_bounds__(512) void k_gemm_g(const __hip_bfloat16* __restrict__ A,
                                                const __bf16* __restrict__ pB,
                                                const float* __restrict__ bias,
                                                __bf16* __restrict__ G2) {
  const int wv = threadIdx.x >> 6, lane = threadIdx.x & 63;
  const int lr = lane & 15, lg = lane >> 4;
  const int r0 = blockIdx.x * 32;
  f32x4 z4 = {0.f, 0.f, 0.f, 0.f};
  f32x4 acc[2][6];
#pragma unroll
  for (int mt = 0; mt < 2; ++mt)
#pragma unroll
    for (int n = 0; n < 6; ++n) acc[mt][n] = z4;
#pragma unroll
  for (int kt = 0; kt < 4; ++kt) {
    bf16x8 a[2];
#pragma unroll
    for (int mt = 0; mt < 2; ++mt)
      a[mt] = *(const bf16x8*)(A + (size_t)(r0 + mt * 16 + lr) * 128 + kt * 32 + lg * 8);
#pragma unroll
    for (int n = 0; n < 6; ++n) {
      bf16x8 b = *(const bf16x8*)(pB + (((size_t)kt * 48 + wv * 6 + n) * 64 + lane) * 8);
      acc[0][n] = MFMA16(a[0], b, acc[0][n], 0, 0, 0);
      acc[1][n] = MFMA16(a[1], b, acc[1][n], 0, 0, 0);
    }
  }
#pragma unroll
  for (int mt = 0; mt < 2; ++mt)
#pragma unroll
    for (int n = 0; n < 6; ++n) {
      int col = wv * 96 + n * 16 + lr;
      int gate = col >> 8, wvc = (col >> 5) & 7, nt = (col >> 4) & 1;
      float bc = bias[col];
#pragma unroll
      for (int r = 0; r < 4; ++r) {
        int row = r0 + mt * 16 + lg * 4 + r;
        G2[(size_t)row * 1024 + wvc * 128 + lr * 8 + gate * 2 + nt] = (__bf16)(acc[mt][n][r] + bc);
      }
    }
}

// ------------------------------------------------------ fused RNN kernel
__device__ void cont_body(char* smem, const __bf16* __restrict__ G2,
                          const float* __restrict__ dtc,
                          const unsigned char* __restrict__ pU8,
                          const float* __restrict__ wt, float* __restrict__ hcont,
                          int blk) {
  unsigned char(*hbuf)[16 * 256] = (unsigned char(*)[16 * 256])smem;  // 8 KB
  unsigned char(*uL)[30 * 512] = (unsigned char(*)[30 * 512])(smem + 8192);  // 120 KB
  float* dl = (float*)(smem + 8192 + 122880);                                // 8 KB
  const int wv = threadIdx.x >> 6, lane = threadIdx.x & 63;
  const int lr = lane & 15, lg = lane >> 4;
  const int p0 = blk * 16;
  for (int idx = threadIdx.x; idx < 2048; idx += 512)
    dl[idx] = dtc[(p0 + (idx >> 7)) * 128 + (idx & 127)];
  for (int i = threadIdx.x; i < 8 * 30 * 64; i += 512) {
    int l = i & 63;
    int fw = i >> 6;
    int f = fw % 30;
    int w = fw / 30;
    int kt = 3 + f / 6;
    int gi = f % 6;
    *(uint2*)&uL[w][(size_t)f * 512 + l * 8] =
        *(const uint2*)(pU8 + (((size_t)kt * 48 + (gi >> 1) * 16 + w * 2 + (gi & 1)) * 64 + l) * 8);
  }
  long fr[3][6];
#pragma unroll
  for (int kt = 0; kt < 3; ++kt)
#pragma unroll
    for (int gi = 0; gi < 6; ++gi)
      fr[kt][gi] =
          *(const long*)(pU8 + (((size_t)kt * 48 + (gi >> 1) * 16 + wv * 2 + (gi & 1)) * 64 + lane) * 8);

  float wtv[2];
#pragma unroll
  for (int nt = 0; nt < 2; ++nt) wtv[nt] = wt[wv * 32 + nt * 16 + lr];
  float h[2][4];
#pragma unroll
  for (int nt = 0; nt < 2; ++nt)
#pragma unroll
    for (int r = 0; r < 4; ++r) h[nt][r] = 0.f;

  const uint4* G2v = (const uint4*)G2;
  const size_t gb0 = (size_t)(p0 + lg * 4) * 16384 + wv * 16 + lr;
  __syncthreads();

  for (int t = 0; t < 128; ++t) {
    unsigned char* hb = hbuf[t & 1];
    uint4 Gv[4];
#pragma unroll
    for (int r = 0; r < 4; ++r) Gv[r] = G2v[gb0 + (size_t)r * 16384 + (size_t)t * 128];
    float hd[2][4];
#pragma unroll
    for (int r = 0; r < 4; ++r) {
      float dtv = dl[(lg * 4 + r) * 128 + t];
#pragma unroll
      for (int nt = 0; nt < 2; ++nt) hd[nt][r] = h[nt][r] * __expf(-fmaxf(dtv * wtv[nt], 0.f));
    }
    const int c0 = wv * 32 + lr, c1 = wv * 32 + 16 + lr;
#pragma unroll
    for (int r = 0; r < 4; ++r) {
      int row = lg * 4 + r;
      int sw = (row & 15) << 3;
      unsigned pk = cvt2fp8(hd[0][r] * 16.f, hd[1][r] * 16.f);
      hb[row * 256 + (c0 ^ sw)] = (unsigned char)pk;
      hb[row * 256 + (c1 ^ sw)] = (unsigned char)(pk >> 8);
    }
    __syncthreads();
    f32x4 acc[3][2];
#pragma unroll
    for (int g = 0; g < 3; ++g)
#pragma unroll
      for (int nt = 0; nt < 2; ++nt) acc[g][nt] = f32x4{0.f, 0.f, 0.f, 0.f};
#pragma unroll
    for (int kt = 0; kt < 8; ++kt) {
      long a = *(const long*)&hb[lr * 256 + ((kt * 32 + lg * 8) ^ ((lr & 15) << 3))];
#pragma unroll
      for (int gi = 0; gi < 6; ++gi) {
        long b = (kt < 3) ? fr[kt][gi]
                          : *(const long*)&uL[wv][(size_t)((kt - 3) * 6 + gi) * 512 + lane * 8];
        acc[gi >> 1][gi & 1] = MFMA8(a, b, acc[gi >> 1][gi & 1], 0, 0, 0);
      }
    }
#pragma unroll
    for (int nt = 0; nt < 2; ++nt)
#pragma unroll
      for (int r = 0; r < 4; ++r) {
        unsigned uz = nt ? (Gv[r].x >> 16) : (Gv[r].x & 0xffffu);
        unsigned ur = nt ? (Gv[r].y >> 16) : (Gv[r].y & 0xffffu);
        unsigned un = nt ? (Gv[r].z >> 16) : (Gv[r].z & 0xffffu);
        const float us = 0.0078125f;  // 1/(16*8)
        float zz = sigm(bfu(uz) + acc[0][nt][r] * us);
        float rr = sigm(bfu(ur) + acc[1][nt][r] * us);
        float nn = tanh_fast(bfu(un) + rr * acc[2][nt][r] * us);
        float hnew = (1.f - zz) * hd[nt][r] + zz * nn;
        h[nt][r] = hnew;
        if (t >= 124)
          hcont[((size_t)(p0 + lg * 4 + r) * 4 + (t - 124)) * 256 + wv * 32 + nt * 16 + lr] = hnew;
      }
  }
}

// main RNN: in-loop e-GEMM (xself + em) + u-GEMM, nt-split (acc 32/pass).
__device__ void main_body(char* smem, const __bf16* __restrict__ em,
                          const float* __restrict__ dtm,
                          const __bf16* __restrict__ xself_bf,
                          const __bf16* __restrict__ pWs, const __bf16* __restrict__ pWe,
                          const __bf16* __restrict__ pU, const float* __restrict__ bg,
                          const float* __restrict__ wt, float* __restrict__ hmain,
                          int blk) {
  __bf16(*hbuf)[32 * 256] = (__bf16(*)[32 * 256])smem;  // 2 x 16KB
  float* dl = (float*)(smem + 32768);                   // 1.9 KB
  const int wv = threadIdx.x >> 6, lane = threadIdx.x & 63;
  const int lr = lane & 15, lg = lane >> 4;
  const int n0 = blk * 32;
  f32x4 z4 = {0.f, 0.f, 0.f, 0.f};
  for (int idx = threadIdx.x; idx < KK * 32; idx += 512)
    dl[idx] = dtm[(idx >> 5) * 8192 + n0 + (idx & 31)];
  float wtv[2], bz[2], br[2], bn[2];
#pragma unroll
  for (int nt = 0; nt < 2; ++nt) {
    int c = wv * 32 + nt * 16 + lr;
    wtv[nt] = wt[c];
    bz[nt] = bg[c];
    br[nt] = bg[c + 256];
    bn[nt] = bg[c + 512];
  }
  float h[2][2][4];
#pragma unroll
  for (int mt = 0; mt < 2; ++mt)
#pragma unroll
    for (int nt = 0; nt < 2; ++nt)
#pragma unroll
      for (int r = 0; r < 4; ++r) h[mt][nt][r] = 0.f;
  __syncthreads();

  for (int t = 0; t < KK; ++t) {
    __bf16* hb = hbuf[t & 1];
#pragma unroll
    for (int mt = 0; mt < 2; ++mt)
#pragma unroll
      for (int r = 0; r < 4; ++r) {
        float dtv = dl[t * 32 + mt * 16 + lg * 4 + r];
        int row = mt * 16 + lg * 4 + r;
#pragma unroll
        for (int nt = 0; nt < 2; ++nt) {
          float hdv = h[mt][nt][r] * __expf(-fmaxf(dtv * wtv[nt], 0.f));
          hb[((row * 256) + (wv * 32 + nt * 16 + lr)) ^ ((row & 7) << 3)] = (__bf16)hdv;
        }
      }
    __syncthreads();

    // two nt passes; per pass acc[4][2] = 32 regs: 0=z,1=r,2=g_n,3=u_n
#pragma unroll
    for (int ntp = 0; ntp < 2; ++ntp) {
      f32x4 acc[4][2];
#pragma unroll
      for (int a4 = 0; a4 < 4; ++a4)
#pragma unroll
        for (int mt = 0; mt < 2; ++mt) acc[a4][mt] = z4;
      // u-GEMM (K=256) from LDS hd -> z, r, u_n
#pragma unroll 2
      for (int kt = 0; kt < 8; ++kt) {
        bf16x8 a[2];
#pragma unroll
        for (int mt = 0; mt < 2; ++mt) {
          int row = mt * 16 + lr;
          int s = ((row * 256) + (kt * 32 + lg * 8)) ^ ((row & 7) << 3);
          a[mt] = *(const bf16x8*)&hb[s];
        }
#pragma unroll
        for (int g = 0; g < 3; ++g) {
          const int ai = (g < 2) ? g : 3;
          bf16x8 b = *(const bf16x8*)(pU + (((size_t)kt * 48 + g * 16 + wv * 2 + ntp) * 64 + lane) * 8);
#pragma unroll
          for (int mt = 0; mt < 2; ++mt) acc[ai][mt] = MFMA16(a[mt], b, acc[ai][mt], 0, 0, 0);
        }
      }
      // e-GEMM (K=256): kt0-3 xself, kt4-7 em -> z, r, g_n
#pragma unroll 2
      for (int kt = 0; kt < 8; ++kt) {
        bf16x8 a[2];
#pragma unroll
        for (int mt = 0; mt < 2; ++mt) {
          if (kt < 4)
            a[mt] = *(const bf16x8*)(xself_bf + (size_t)((n0 + mt * 16) >> 4) * 128 + kt * 32 + lg * 8);
          else
            a[mt] = *(const bf16x8*)(em + ((size_t)t * 8192 + n0 + mt * 16 + lr) * 128 +
                                     (kt - 4) * 32 + lg * 8);
        }
        const __bf16* pB = (kt < 4) ? (pWs + (size_t)kt * 48 * 512)
                                    : (pWe + (size_t)(kt - 4) * 48 * 512);
#pragma unroll
        for (int g = 0; g < 3; ++g) {
          bf16x8 b = *(const bf16x8*)(pB + (((size_t)g * 16 + wv * 2 + ntp) * 64 + lane) * 8);
#pragma unroll
          for (int mt = 0; mt < 2; ++mt) acc[g][mt] = MFMA16(a[mt], b, acc[g][mt], 0, 0, 0);
        }
      }
      // gates for this nt half
#pragma unroll
      for (int mt = 0; mt < 2; ++mt)
#pragma unroll
        for (int r = 0; r < 4; ++r) {
          float dtv = dl[t * 32 + mt * 16 + lg * 4 + r];
          float hdv = h[mt][ntp][r] * __expf(-fmaxf(dtv * wtv[ntp], 0.f));
          float zz = sigm(acc[0][mt][r] + bz[ntp]);
          float rr = sigm(acc[1][mt][r] + br[ntp]);
          float nn = tanh_fast(acc[2][mt][r] + bn[ntp] + rr * acc[3][mt][r]);
          h[mt][ntp][r] = (1.f - zz) * hdv + zz * nn;
        }
    }
  }
  __syncthreads();
#pragma unroll
  for (int mt = 0; mt < 2; ++mt)
#pragma unroll
    for (int nt = 0; nt < 2; ++nt)
#pragma unroll
      for (int r = 0; r < 4; ++r)
        hmain[(size_t)(n0 + mt * 16 + lg * 4 + r) * 256 + wv * 32 + nt * 16 + lr] = h[mt][nt][r];
}

__global__ __launch_bounds__(512) void k_rnn_fused(
    const __bf16* __restrict__ G2, const float* __restrict__ dtc,
    const unsigned char* __restrict__ pU8, const float* __restrict__ wt_c,
    float* __restrict__ hcont, const __bf16* __restrict__ em,
    const float* __restrict__ dtm, const __bf16* __restrict__ xself_bf,
    const __bf16* __restrict__ pWs, const __bf16* __restrict__ pWe,
    const __bf16* __restrict__ pU, const float* __restrict__ b_rnn,
    const float* __restrict__ wt_m, float* __restrict__ hmain) {
  __shared__ __align__(16) char smem[8192 + 122880 + 8192];  // 136 KB union
  if (blockIdx.x < 8)
    cont_body(smem, G2, dtc, pU8, wt_c, hcont, blockIdx.x);
  else
    main_body(smem, em, dtm, xself_bf, pWs, pWe, pU, b_rnn, wt_m, hmain, blockIdx.x - 8);
}

// ------------------------------------------------------------------ tail
__global__ __launch_bounds__(256) void k_att(const float* __restrict__ hmain,
                                             const float* __restrict__ xself,
                                             const float* __restrict__ hc,
                                             const float* __restrict__ Wv,
                                             const float* __restrict__ bv,
                                             float* __restrict__ hh,
                                             __bf16* __restrict__ hh_bf) {
  int b = blockIdx.x, tid = threadIdx.x;
  __shared__ float hl[16 * 256];
  __shared__ float aa[16 * 4];
  for (int idx = tid; idx < 4096; idx += 256) hl[idx] = hmain[(size_t)b * SS * HH + idx];
  __syncthreads();
  if (tid < 64) {
    int s = tid >> 2, m = tid & 3;
    float acc = bv[m];
    for (int j = 0; j < 256; ++j)
      acc += hl[s * 256 + j] * Wv[j * 4 + m] + hl[j] * Wv[(256 + j) * 4 + m];
    aa[s * 4 + m] = tanh_fast(acc);
  }
  __syncthreads();
  if (tid < 4) {
    int m = tid;
    float mx = -1e30f;
    for (int s = 0; s < 16; ++s) mx = fmaxf(mx, aa[s * 4 + m]);
    float sum = 0.f;
    for (int s = 0; s < 16; ++s) sum += __expf(aa[s * 4 + m] - mx);
    float inv = 1.f / sum;
    for (int s = 0; s < 16; ++s) aa[s * 4 + m] = __expf(aa[s * 4 + m] - mx) * inv;
  }
  __syncthreads();
  float a0 = 0.f, a1 = 0.f, a2 = 0.f, a3 = 0.f;
  for (int s = 0; s < 16; ++s) {
    float hv = hl[s * 256 + tid];
    a0 = fmaf(aa[s * 4 + 0], hv, a0);
    a1 = fmaf(aa[s * 4 + 1], hv, a1);
    a2 = fmaf(aa[s * 4 + 2], hv, a2);
    a3 = fmaf(aa[s * 4 + 3], hv, a3);
  }
  float* hb = hh + (size_t)b * 1664;
  __bf16* hf = hh_bf + (size_t)b * 1664;
  hb[384 + 0 * 256 + tid] = a0;
  hb[384 + 1 * 256 + tid] = a1;
  hb[384 + 2 * 256 + tid] = a2;
  hb[384 + 3 * 256 + tid] = a3;
  hf[384 + 0 * 256 + tid] = (__bf16)a0;
  hf[384 + 1 * 256 + tid] = (__bf16)a1;
  hf[384 + 2 * 256 + tid] = (__bf16)a2;
  hf[384 + 3 * 256 + tid] = (__bf16)a3;
  if (tid < 128) {
    hb[tid] = xself[b * DD + tid];
    hf[tid] = (__bf16)xself[b * DD + tid];
  }
  hb[128 + tid] = hl[tid];
  hf[128 + tid] = (__bf16)hl[tid];
  float hcv = hc[(size_t)b * HH + tid];
  hb[1408 + tid] = hcv;
  hf[1408 + tid] = (__bf16)hcv;
}

// MFMA MLP layer: C = leakyrelu(A @ W + b)
__global__ __launch_bounds__(512) void k_mlp_mfma(const __bf16* __restrict__ A,
                                                  const __bf16* __restrict__ pW,
                                                  const float* __restrict__ bias,
                                                  __bf16* __restrict__ C, int K, int N) {
  const int wv = threadIdx.x >> 6, lane = threadIdx.x & 63;
  const int lr = lane & 15, lg = lane >> 4;
  const int r0 = blockIdx.y * 32;
  const int c0 = blockIdx.x * 256;
  const int NT = N >> 4;
  const int KT = K >> 5;
  f32x4 acc[2][2];
#pragma unroll
  for (int mt = 0; mt < 2; ++mt)
#pragma unroll
    for (int nt = 0; nt < 2; ++nt) acc[mt][nt] = f32x4{0.f, 0.f, 0.f, 0.f};
  for (int kt = 0; kt < KT; ++kt) {
    bf16x8 a[2];
#pragma unroll
    for (int mt = 0; mt < 2; ++mt)
      a[mt] = *(const bf16x8*)(A + (size_t)(r0 + mt * 16 + lr) * K + kt * 32 + lg * 8);
#pragma unroll
    for (int nt = 0; nt < 2; ++nt) {
      bf16x8 b = *(const bf16x8*)(pW + (((size_t)kt * NT + (c0 >> 4) + wv * 2 + nt) * 64 + lane) * 8);
#pragma unroll
      for (int mt = 0; mt < 2; ++mt) acc[mt][nt] = MFMA16(a[mt], b, acc[mt][nt], 0, 0, 0);
    }
  }
#pragma unroll
  for (int nt = 0; nt < 2; ++nt) {
    int col = c0 + wv * 32 + nt * 16 + lr;
    float bc = bias[col];
#pragma unroll
    for (int mt = 0; mt < 2; ++mt)
#pragma unroll
      for (int r = 0; r < 4; ++r) {
        float v = acc[mt][nt][r] + bc;
        v = v > 0.f ? v : 0.01f * v;
        C[(size_t)(r0 + mt * 16 + lg * 4 + r) * N + col] = (__bf16)v;
      }
  }
}

__global__ __launch_bounds__(64) void k_head(const __bf16* __restrict__ A,
                                             const float* __restrict__ Wp,
                                             const float* __restrict__ bp,
                                             float* __restrict__ out) {
  int row = blockIdx.x, l = threadIdx.x;
  float acc = 0.f;
  for (int j = l; j < 256; j += 64) acc = fmaf((float)A[(size_t)row * 256 + j], Wp[j], acc);
  for (int o = 32; o; o >>= 1) acc += __shfl_xor(acc, o);
  if (l == 0) out[row] = 1.f / (1.f + __expf(-(acc + bp[0])));
}

extern "C" void kernel_launch(void* const* d_in, const int* in_sizes, int n_in,
                              void* d_out, int out_size, void* d_ws, size_t ws_size,
                              hipStream_t stream) {
  const int* x = (const int*)d_in[0];
  const int* xc = (const int*)d_in[1];
  const int* self_loc = (const int*)d_in[2];
  const float* emb = (const float*)d_in[3];
  const float* W_rnn = (const float*)d_in[4];
  const float* U_rnn = (const float*)d_in[5];
  const float* b_rnn = (const float*)d_in[6];
  const float* wt_rnn = (const float*)d_in[7];
  const float* W_c = (const float*)d_in[8];
  const float* U_c = (const float*)d_in[9];
  const float* b_c = (const float*)d_in[10];
  const float* wt_c = (const float*)d_in[11];
  const float* Wv = (const float*)d_in[12];
  const float* bv = (const float*)d_in[13];
  const float* W0 = (const float*)d_in[14];
  const float* b0 = (const float*)d_in[15];
  const float* W1 = (const float*)d_in[16];
  const float* b1 = (const float*)d_in[17];
  const float* W2 = (const float*)d_in[18];
  const float* b2 = (const float*)d_in[19];
  const float* Wp = (const float*)d_in[20];
  const float* bp = (const float*)d_in[21];
  float* out = (float*)d_out;

  char* ws = (char*)d_ws;
  size_t cur = 0;
  auto alloc = [&](size_t bytes) {
    char* p = ws + cur;
    cur += (bytes + 255) & ~(size_t)255;
    return p;
  };
  float* es = (float*)alloc((size_t)BB * DD * 4);
  float* ns = (float*)alloc(BB * 4);
  unsigned* minu = (unsigned*)alloc(4);
  float* simw = (float*)alloc((size_t)BB * SS * II * 4);
  int* topidx = (int*)alloc((size_t)BB * SS * KK * 4);
  float* xself = (float*)alloc((size_t)BB * DD * 4);
  __bf16* xself_bf = (__bf16*)alloc((size_t)BB * DD * 2);
  float* dtm = (float*)alloc((size_t)KK * 8192 * 4);
  float* dtc = (float*)alloc((size_t)128 * 128 * 4);
  float* hcont = (float*)alloc((size_t)BB * HH * 4);
  float* hh = (float*)alloc((size_t)BB * 1664 * 4);
  __bf16* hh_bf = (__bf16*)alloc((size_t)BB * 1664 * 2);
  __bf16* z0 = (__bf16*)alloc((size_t)BB * 1024 * 2);
  __bf16* z1 = (__bf16*)alloc((size_t)BB * 512 * 2);
  __bf16* z2 = (__bf16*)alloc((size_t)BB * 256 * 2);
  float* hmain = (float*)alloc((size_t)8192 * HH * 4);
  __hip_bfloat16* ec = (__hip_bfloat16*)alloc((size_t)16384 * DD * 2);
  __bf16* em = (__bf16*)alloc((size_t)KK * 8192 * DD * 2);
  __bf16* G2 = (__bf16*)alloc((size_t)16384 * 1024 * 2);
  __bf16* pWs = (__bf16*)alloc((size_t)4 * 48 * 64 * 8 * 2);
  __bf16* pWe = (__bf16*)alloc((size_t)4 * 48 * 64 * 8 * 2);
  __bf16* pU = (__bf16*)alloc((size_t)8 * 48 * 64 * 8 * 2);
  __bf16* pWc = (__bf16*)alloc((size_t)4 * 48 * 64 * 8 * 2);
  unsigned char* pU8 = (unsigned char*)alloc((size_t)8 * 48 * 64 * 8);
  __bf16* pW0 = (__bf16*)alloc((size_t)52 * 64 * 64 * 8 * 2);
  __bf16* pW1 = (__bf16*)alloc((size_t)32 * 32 * 64 * 8 * 2);
  __bf16* pW2 = (__bf16*)alloc((size_t)16 * 16 * 64 * 8 * 2);
  (void)ws_size;

  hipLaunchKernelGGL(k_init, dim3(1), dim3(1), 0, stream, minu);
  hipLaunchKernelGGL(k_eself, dim3(BB), dim3(128), 0, stream, x, self_loc, emb, es, ns);
  hipLaunchKernelGGL(k_cos, dim3(BB * SS), dim3(256), 0, stream, x, emb, es, ns, simw, minu);
  hipLaunchKernelGGL(k_topk, dim3(BB * SS), dim3(64), 0, stream, x, simw, minu, topidx);
  hipLaunchKernelGGL(k_build_main, dim3(1024, KK), dim3(256), 0, stream, x, self_loc, emb,
                     topidx, em, dtm, xself, xself_bf);
  hipLaunchKernelGGL(k_build_cont, dim3(128, 128), dim3(128), 0, stream, xc, emb, ec, dtc);
  hipLaunchKernelGGL(k_pack, dim3(4, 48), dim3(64), 0, stream, W_rnn, pWs);
  hipLaunchKernelGGL(k_pack, dim3(4, 48), dim3(64), 0, stream, W_rnn + 128 * 768, pWe);
  hipLaunchKernelGGL(k_pack, dim3(8, 48), dim3(64), 0, stream, U_rnn, pU);
  hipLaunchKernelGGL(k_pack, dim3(4, 48), dim3(64), 0, stream, W_c, pWc);
  hipLaunchKernelGGL(k_pack8, dim3(8, 48), dim3(64), 0, stream, U_c, pU8);
  hipLaunchKernelGGL(k_packN, dim3(52, 64), dim3(64), 0, stream, W0, pW0, 1024);
  hipLaunchKernelGGL(k_packN, dim3(32, 32), dim3(64), 0, stream, W1, pW1, 512);
  hipLaunchKernelGGL(k_packN, dim3(16, 16), dim3(64), 0, stream, W2, pW2, 256);
  hipLaunchKernelGGL(k_gemm_g, dim3(512), dim3(512), 0, stream, ec, pWc, b_c, G2);
  hipLaunchKernelGGL(k_rnn_fused, dim3(264), dim3(512), 0, stream, G2, dtc, pU8, wt_c,
                     hcont, em, dtm, xself_bf, pWs, pWe, pU, b_rnn, wt_rnn, hmain);
  hipLaunchKernelGGL(k_att, dim3(BB), dim3(256), 0, stream, hmain, xself, hcont, Wv, bv, hh,
                     hh_bf);
  hipLaunchKernelGGL(k_mlp_mfma, dim3(4, 16), dim3(512), 0, stream, hh_bf, pW0, b0, z0,
                     1664, 1024);
  hipLaunchKernelGGL(k_mlp_mfma, dim3(2, 16), dim3(512), 0, stream, z0, pW1, b1, z1, 1024,
                     512);
  hipLaunchKernelGGL(k_mlp_mfma, dim3(1, 16), dim3(512), 0, stream, z1, pW2, b2, z2, 512,
                     256);
  hipLaunchKernelGGL(k_head, dim3(BB), dim3(64), 0, stream, z2, Wp, bp, out);
}

// Round 19
// 766.059 us; speedup vs baseline: 1.3050x; 1.0109x over previous
//
#include <hip/hip_runtime.h>
#include <hip/hip_bf16.h>

// SearchPredictModel round 19: R18 + top-K ordering fix.
//  - phase 0c now uses ballot/popcount compaction (ascending-index order,
//    matching reference's sort(top_k(...)[1])). R18 stored by rank -> wrong
//    sequence order -> absmax fail.
//  - everything else identical to R18.

#define PAD_TOK 200000
#define DD 128
#define HH 256
#define KK 15
#define BB 512
#define SS 16
#define II 64

typedef __bf16 bf16x8 __attribute__((ext_vector_type(8)));
typedef __bf16 bf16x4 __attribute__((ext_vector_type(4)));
typedef float f32x4 __attribute__((ext_vector_type(4)));
#define MFMA16 __builtin_amdgcn_mfma_f32_16x16x32_bf16
#define MFMA8 __builtin_amdgcn_mfma_f32_16x16x32_fp8_fp8

__device__ __forceinline__ float sigm(float x) { return 1.f / (1.f + __expf(-x)); }
__device__ __forceinline__ float tanh_fast(float x) {
  x = fminf(fmaxf(x, -15.f), 15.f);
  float e2 = __expf(2.f * x);
  return (e2 - 1.f) / (e2 + 1.f);
}
__device__ __forceinline__ float bfu(unsigned u16) { return __uint_as_float(u16 << 16); }

// float -> fp8 e4m3 (OCP), RNE, FTZ below 2^-6 (software fallback)
__device__ __forceinline__ unsigned char f2fp8(float x) {
  unsigned u = __float_as_uint(x);
  unsigned s = (u >> 31) << 7;
  int e = (int)((u >> 23) & 0xff) - 127;
  if (e < -6) return (unsigned char)s;
  unsigned m = (u >> 20) & 7;
  unsigned rest = u & 0xFFFFF;
  if (rest > 0x80000 || (rest == 0x80000 && (m & 1))) {
    ++m;
    if (m == 8) {
      m = 0;
      ++e;
    }
  }
  if (e > 7) {
    e = 7;
    m = 6;
  }
  return (unsigned char)(s | ((unsigned)(e + 7) << 3) | m);
}

__device__ __forceinline__ unsigned cvt2fp8(float a, float b) {
#if __has_builtin(__builtin_amdgcn_cvt_pk_fp8_f32)
  return (unsigned)__builtin_amdgcn_cvt_pk_fp8_f32(a, b, 0, false) & 0xffffu;
#else
  return (unsigned)f2fp8(a) | ((unsigned)f2fp8(b) << 8);
#endif
}

// ---------------------------------------------------------------- front end
__global__ __launch_bounds__(128) void k_build_cont(const int* __restrict__ xc,
                                                    const float* __restrict__ emb,
                                                    __hip_bfloat16* __restrict__ ec,
                                                    float* __restrict__ dtc) {
  int p = blockIdx.x, t = blockIdx.y, d = threadIdx.x;
  const int* xr = xc + ((size_t)p * 128 + t) * 8;
  float acc = 0.f;
#pragma unroll
  for (int jj = 0; jj < 6; ++jj) acc += emb[(size_t)xr[jj] * DD + d];
  ec[((size_t)p * 128 + t) * DD + d] = __float2bfloat16(acc);
  if (d == 0) dtc[p * 128 + t] = (t > 0) ? ((float)xr[6] - (float)xr[-2]) : 0.f;
}

// ------------------------------------------------- weight fragment packing
__global__ __launch_bounds__(64) void k_pack(const float* __restrict__ B,
                                             __bf16* __restrict__ out) {
  int kt = blockIdx.x, tile = blockIdx.y, lane = threadIdx.x;
  const float* src = B + (size_t)(kt * 32 + (lane >> 4) * 8) * 768 + tile * 16 + (lane & 15);
  __bf16* o = out + (((size_t)(kt * 48 + tile) * 64 + lane) * 8);
#pragma unroll
  for (int i = 0; i < 8; ++i) o[i] = (__bf16)src[(size_t)i * 768];
}

// U_c -> fp8 fragments (x8 scale)
__global__ __launch_bounds__(64) void k_pack8(const float* __restrict__ B,
                                              unsigned char* __restrict__ out) {
  int kt = blockIdx.x, tile = blockIdx.y, lane = threadIdx.x;
  const float* src = B + (size_t)(kt * 32 + (lane >> 4) * 8) * 768 + tile * 16 + (lane & 15);
  unsigned char* o = out + (((size_t)(kt * 48 + tile) * 64 + lane) * 8);
#pragma unroll
  for (int i = 0; i < 8; ++i) o[i] = f2fp8(src[(size_t)i * 768] * 8.f);
}

// general pack for [K x N] f32 -> MFMA fragments
__global__ __launch_bounds__(64) void k_packN(const float* __restrict__ B,
                                              __bf16* __restrict__ out, int N) {
  int kt = blockIdx.x, tile = blockIdx.y, lane = threadIdx.x;
  const float* src = B + (size_t)(kt * 32 + (lane >> 4) * 8) * N + tile * 16 + (lane & 15);
  __bf16* o = out + (((size_t)kt * gridDim.y + tile) * 64 + lane) * 8;
#pragma unroll
  for (int i = 0; i < 8; ++i) o[i] = (__bf16)src[(size_t)i * N];
}

// -------- cont-RNN g precompute: G2 (fragment-packed) = ec@Wc + b
__global__ __launch_bounds__(512) void k_gemm_g(const __hip_bfloat16* __restrict__ A,
                                                const __bf16* __restrict__ pB,
                                                const float* __restrict__ bias,
                                                __bf16* __restrict__ G2) {
  const int wv = threadIdx.x >> 6, lane = threadIdx.x & 63;
  const int lr = lane & 15, lg = lane >> 4;
  const int r0 = blockIdx.x * 32;
  f32x4 z4 = {0.f, 0.f, 0.f, 0.f};
  f32x4 acc[2][6];
#pragma unroll
  for (int mt = 0; mt < 2; ++mt)
#pragma unroll
    for (int n = 0; n < 6; ++n) acc[mt][n] = z4;
#pragma unroll
  for (int kt = 0; kt < 4; ++kt) {
    bf16x8 a[2];
#pragma unroll
    for (int mt = 0; mt < 2; ++mt)
      a[mt] = *(const bf16x8*)(A + (size_t)(r0 + mt * 16 + lr) * 128 + kt * 32 + lg * 8);
#pragma unroll
    for (int n = 0; n < 6; ++n) {
      bf16x8 b = *(const bf16x8*)(pB + (((size_t)kt * 48 + wv * 6 + n) * 64 + lane) * 8);
      acc[0][n] = MFMA16(a[0], b, acc[0][n], 0, 0, 0);
      acc[1][n] = MFMA16(a[1], b, acc[1][n], 0, 0, 0);
    }
  }
#pragma unroll
  for (int mt = 0; mt < 2; ++mt)
#pragma unroll
    for (int n = 0; n < 6; ++n) {
      int col = wv * 96 + n * 16 + lr;
      int gate = col >> 8, wvc = (col >> 5) & 7, nt = (col >> 4) & 1;
      float bc = bias[col];
#pragma unroll
      for (int r = 0; r < 4; ++r) {
        int row = r0 + mt * 16 + lg * 4 + r;
        G2[(size_t)row * 1024 + wvc * 128 + lr * 8 + gate * 2 + nt] = (__bf16)(acc[mt][n][r] + bc);
      }
    }
}

// ------------------------------------------------------ fused RNN kernel
__device__ void cont_body(char* smem, const __bf16* __restrict__ G2,
                          const float* __restrict__ dtc,
                          const unsigned char* __restrict__ pU8,
                          const float* __restrict__ wt, float* __restrict__ hcont,
                          int blk) {
  unsigned char(*hbuf)[16 * 256] = (unsigned char(*)[16 * 256])smem;  // 8 KB
  unsigned char(*uL)[30 * 512] = (unsigned char(*)[30 * 512])(smem + 8192);  // 120 KB
  float* dl = (float*)(smem + 8192 + 122880);                                // 8 KB
  const int wv = threadIdx.x >> 6, lane = threadIdx.x & 63;
  const int lr = lane & 15, lg = lane >> 4;
  const int p0 = blk * 16;
  for (int idx = threadIdx.x; idx < 2048; idx += 512)
    dl[idx] = dtc[(p0 + (idx >> 7)) * 128 + (idx & 127)];
  for (int i = threadIdx.x; i < 8 * 30 * 64; i += 512) {
    int l = i & 63;
    int fw = i >> 6;
    int f = fw % 30;
    int w = fw / 30;
    int kt = 3 + f / 6;
    int gi = f % 6;
    *(uint2*)&uL[w][(size_t)f * 512 + l * 8] =
        *(const uint2*)(pU8 + (((size_t)kt * 48 + (gi >> 1) * 16 + w * 2 + (gi & 1)) * 64 + l) * 8);
  }
  long fr[3][6];
#pragma unroll
  for (int kt = 0; kt < 3; ++kt)
#pragma unroll
    for (int gi = 0; gi < 6; ++gi)
      fr[kt][gi] =
          *(const long*)(pU8 + (((size_t)kt * 48 + (gi >> 1) * 16 + wv * 2 + (gi & 1)) * 64 + lane) * 8);

  float wtv[2];
#pragma unroll
  for (int nt = 0; nt < 2; ++nt) wtv[nt] = wt[wv * 32 + nt * 16 + lr];
  float h[2][4];
#pragma unroll
  for (int nt = 0; nt < 2; ++nt)
#pragma unroll
    for (int r = 0; r < 4; ++r) h[nt][r] = 0.f;

  const uint4* G2v = (const uint4*)G2;
  const size_t gb0 = (size_t)(p0 + lg * 4) * 16384 + wv * 16 + lr;
  __syncthreads();

  for (int t = 0; t < 128; ++t) {
    unsigned char* hb = hbuf[t & 1];
    uint4 Gv[4];
#pragma unroll
    for (int r = 0; r < 4; ++r) Gv[r] = G2v[gb0 + (size_t)r * 16384 + (size_t)t * 128];
    float hd[2][4];
#pragma unroll
    for (int r = 0; r < 4; ++r) {
      float dtv = dl[(lg * 4 + r) * 128 + t];
#pragma unroll
      for (int nt = 0; nt < 2; ++nt) hd[nt][r] = h[nt][r] * __expf(-fmaxf(dtv * wtv[nt], 0.f));
    }
    const int c0 = wv * 32 + lr, c1 = wv * 32 + 16 + lr;
#pragma unroll
    for (int r = 0; r < 4; ++r) {
      int row = lg * 4 + r;
      int sw = (row & 15) << 3;
      unsigned pk = cvt2fp8(hd[0][r] * 16.f, hd[1][r] * 16.f);
      hb[row * 256 + (c0 ^ sw)] = (unsigned char)pk;
      hb[row * 256 + (c1 ^ sw)] = (unsigned char)(pk >> 8);
    }
    __syncthreads();
    f32x4 acc[3][2];
#pragma unroll
    for (int g = 0; g < 3; ++g)
#pragma unroll
      for (int nt = 0; nt < 2; ++nt) acc[g][nt] = f32x4{0.f, 0.f, 0.f, 0.f};
#pragma unroll
    for (int kt = 0; kt < 8; ++kt) {
      long a = *(const long*)&hb[lr * 256 + ((kt * 32 + lg * 8) ^ ((lr & 15) << 3))];
#pragma unroll
      for (int gi = 0; gi < 6; ++gi) {
        long b = (kt < 3) ? fr[kt][gi]
                          : *(const long*)&uL[wv][(size_t)((kt - 3) * 6 + gi) * 512 + lane * 8];
        acc[gi >> 1][gi & 1] = MFMA8(a, b, acc[gi >> 1][gi & 1], 0, 0, 0);
      }
    }
#pragma unroll
    for (int nt = 0; nt < 2; ++nt)
#pragma unroll
      for (int r = 0; r < 4; ++r) {
        unsigned uz = nt ? (Gv[r].x >> 16) : (Gv[r].x & 0xffffu);
        unsigned ur = nt ? (Gv[r].y >> 16) : (Gv[r].y & 0xffffu);
        unsigned un = nt ? (Gv[r].z >> 16) : (Gv[r].z & 0xffffu);
        const float us = 0.0078125f;  // 1/(16*8)
        float zz = sigm(bfu(uz) + acc[0][nt][r] * us);
        float rr = sigm(bfu(ur) + acc[1][nt][r] * us);
        float nn = tanh_fast(bfu(un) + rr * acc[2][nt][r] * us);
        float hnew = (1.f - zz) * hd[nt][r] + zz * nn;
        h[nt][r] = hnew;
        if (t >= 124)
          hcont[((size_t)(p0 + lg * 4 + r) * 4 + (t - 124)) * 256 + wv * 32 + nt * 16 + lr] = hnew;
      }
  }
}

// main: phase 0 = eself/cos/topk/build (block-local); phase 2 = recurrence.
__device__ void main_body(char* smem, const int* __restrict__ x,
                          const int* __restrict__ self_loc,
                          const float* __restrict__ emb,
                          const __bf16* __restrict__ pWs, const __bf16* __restrict__ pWe,
                          const __bf16* __restrict__ pU, const float* __restrict__ bg,
                          const float* __restrict__ wt, __bf16* __restrict__ em,
                          float* __restrict__ xself, float* __restrict__ hmain,
                          int blk) {
  __bf16(*hbuf)[32 * 256] = (__bf16(*)[32 * 256])smem;  // 2 x 16KB
  float* dl = (float*)(smem + 32768);                   // KK*32 f32 (1920B)
  float* esL = (float*)(smem + 34944);                  // 2*128 f32
  float* nsL = (float*)(smem + 35968);                  // 2 f32
  __bf16* xsbf = (__bf16*)(smem + 36000);               // 2*128 bf16 (512B)
  float* simL = (float*)(smem + 36544);                 // 32*64 f32 (8KB)
  int* tpxL = (int*)(smem + 44736);                     // 32*15 int (1920B)
  const int tid = threadIdx.x;
  const int wv = tid >> 6, lane = tid & 63;
  const int lr = lane & 15, lg = lane >> 4;
  const int n0 = blk * 32;
  const int b0 = n0 >> 4;
  f32x4 z4 = {0.f, 0.f, 0.f, 0.f};

  // ---- phase 0a: e_self + norms for the block's 2 b-groups
  if (tid < 256) {
    int bb = tid >> 7, d = tid & 127;
    int bgl = b0 + bb;
    int tok = x[((size_t)(bgl * SS) * II + self_loc[bgl]) * 8 + 5];
    esL[bb * 128 + d] = emb[(size_t)tok * DD + d];
  }
  __syncthreads();
  if (tid < 128) {
    int bb = tid >> 6, l = tid & 63;
    float v0 = esL[bb * 128 + l], v1 = esL[bb * 128 + 64 + l];
    float ss = v0 * v0 + v1 * v1;
    for (int o = 32; o; o >>= 1) ss += __shfl_xor(ss, o);
    if (l == 0) nsL[bb] = fmaxf(sqrtf(ss), 1e-8f);
  }
  __syncthreads();
  // ---- phase 0b: cos -> sim (4 lanes per (row,item)); neg fill = -3
  for (int it = 0; it < 16; ++it) {
    int pr = it * 128 + (tid >> 2);
    int row = pr >> 6, item = pr & 63, q = tid & 3;
    const int* xr = x + ((size_t)(n0 + row) * II + item) * 8;
    int tok = xr[5];
    int first = xr[0];
    const float4* ep = (const float4*)(emb + (size_t)tok * DD + q * 32);
    const float4* sp = (const float4*)(esL + (row >> 4) * 128 + q * 32);
    float dot = 0.f, ss = 0.f;
#pragma unroll
    for (int j = 0; j < 8; ++j) {
      float4 a = ep[j];
      float4 e = sp[j];
      dot += a.x * e.x + a.y * e.y + a.z * e.z + a.w * e.w;
      ss += a.x * a.x + a.y * a.y + a.z * a.z + a.w * a.w;
    }
    dot += __shfl_xor(dot, 1);
    ss += __shfl_xor(ss, 1);
    dot += __shfl_xor(dot, 2);
    ss += __shfl_xor(ss, 2);
    if (q == 0)
      simL[row * 64 + item] =
          (first != PAD_TOK) ? dot / (fmaxf(sqrtf(ss), 1e-8f) * nsL[row >> 4]) : -3.0f;
  }
  __syncthreads();
  // ---- phase 0c: top-K, ASCENDING-INDEX order via ballot compaction
  // (one wave per row: lane == item)
  for (int it = 0; it < 4; ++it) {
    int pr = it * 512 + tid;
    int row = pr >> 6, item = pr & 63;
    float s = simL[row * 64 + item];
    int rank = 0;
    for (int j = 0; j < 64; ++j) {
      float o = simL[row * 64 + j];
      rank += (o > s) || (o == s && j < item);
    }
    bool sel = rank < KK;
    unsigned long long mask = __ballot(sel);
    if (sel) {
      int pos = __popcll(mask & ((1ull << item) - 1ull));
      tpxL[row * KK + pos] = item;
    }
  }
  __syncthreads();
  // ---- phase 0d: gather/sum -> em (global, block rows), dl, xself
  for (int t = 0; t < KK; ++t) {
    int rr = tid >> 5, q = tid & 31;
#pragma unroll
    for (int pass = 0; pass < 2; ++pass) {
      int rloc = pass * 16 + rr;
      int ng = n0 + rloc;
      int bb = ng >> 4, s = ng & 15;
      bool ovr = (s == 0) && (t == KK - 1);
      int item = ovr ? self_loc[bb] : tpxL[rloc * KK + t];
      const int* xr = x + ((size_t)ng * II + item) * 8;
      float4 a4 = {0.f, 0.f, 0.f, 0.f};
#pragma unroll
      for (int jj = 0; jj < 6; ++jj) {
        float4 v = *(const float4*)(emb + (size_t)xr[jj] * DD + q * 4);
        a4.x += v.x;
        a4.y += v.y;
        a4.z += v.z;
        a4.w += v.w;
      }
      bf16x4 ov = {(__bf16)a4.x, (__bf16)a4.y, (__bf16)a4.z, (__bf16)a4.w};
      *(bf16x4*)(em + ((size_t)t * 8192 + ng) * DD + q * 4) = ov;
      if (ovr) {
        *(float4*)(xself + bb * DD + q * 4) = a4;
        *(bf16x4*)(xsbf + (bb - b0) * 128 + q * 4) = ov;
      }
      if (q == 0) {
        float dtv = 0.f;
        if (t > 0) {
          int pitem = tpxL[rloc * KK + t - 1];
          dtv = (float)xr[6] - (float)x[((size_t)ng * II + pitem) * 8 + 6];
        }
        dl[t * 32 + rloc] = dtv;
      }
    }
  }
  __syncthreads();

  // ---- phase 2: recurrence (R17 nt-split, no spill)
  float wtv[2], bz[2], br[2], bn[2];
#pragma unroll
  for (int nt = 0; nt < 2; ++nt) {
    int c = wv * 32 + nt * 16 + lr;
    wtv[nt] = wt[c];
    bz[nt] = bg[c];
    br[nt] = bg[c + 256];
    bn[nt] = bg[c + 512];
  }
  float h[2][2][4];
#pragma unroll
  for (int mt = 0; mt < 2; ++mt)
#pragma unroll
    for (int nt = 0; nt < 2; ++nt)
#pragma unroll
      for (int r = 0; r < 4; ++r) h[mt][nt][r] = 0.f;

  for (int t = 0; t < KK; ++t) {
    __bf16* hb = hbuf[t & 1];
#pragma unroll
    for (int mt = 0; mt < 2; ++mt)
#pragma unroll
      for (int r = 0; r < 4; ++r) {
        float dtv = dl[t * 32 + mt * 16 + lg * 4 + r];
        int row = mt * 16 + lg * 4 + r;
#pragma unroll
        for (int nt = 0; nt < 2; ++nt) {
          float hdv = h[mt][nt][r] * __expf(-fmaxf(dtv * wtv[nt], 0.f));
          hb[((row * 256) + (wv * 32 + nt * 16 + lr)) ^ ((row & 7) << 3)] = (__bf16)hdv;
        }
      }
    __syncthreads();
#pragma unroll
    for (int ntp = 0; ntp < 2; ++ntp) {
      f32x4 acc[4][2];
#pragma unroll
      for (int a4 = 0; a4 < 4; ++a4)
#pragma unroll
        for (int mt = 0; mt < 2; ++mt) acc[a4][mt] = z4;
#pragma unroll 2
      for (int kt = 0; kt < 8; ++kt) {
        bf16x8 a[2];
#pragma unroll
        for (int mt = 0; mt < 2; ++mt) {
          int row = mt * 16 + lr;
          int s = ((row * 256) + (kt * 32 + lg * 8)) ^ ((row & 7) << 3);
          a[mt] = *(const bf16x8*)&hb[s];
        }
#pragma unroll
        for (int g = 0; g < 3; ++g) {
          const int ai = (g < 2) ? g : 3;
          bf16x8 b = *(const bf16x8*)(pU + (((size_t)kt * 48 + g * 16 + wv * 2 + ntp) * 64 + lane) * 8);
#pragma unroll
          for (int mt = 0; mt < 2; ++mt) acc[ai][mt] = MFMA16(a[mt], b, acc[ai][mt], 0, 0, 0);
        }
      }
#pragma unroll 2
      for (int kt = 0; kt < 8; ++kt) {
        bf16x8 a[2];
#pragma unroll
        for (int mt = 0; mt < 2; ++mt) {
          if (kt < 4)
            a[mt] = *(const bf16x8*)(xsbf + mt * 128 + kt * 32 + lg * 8);
          else
            a[mt] = *(const bf16x8*)(em + ((size_t)t * 8192 + n0 + mt * 16 + lr) * 128 +
                                     (kt - 4) * 32 + lg * 8);
        }
        const __bf16* pB = (kt < 4) ? (pWs + (size_t)kt * 48 * 512)
                                    : (pWe + (size_t)(kt - 4) * 48 * 512);
#pragma unroll
        for (int g = 0; g < 3; ++g) {
          bf16x8 b = *(const bf16x8*)(pB + (((size_t)g * 16 + wv * 2 + ntp) * 64 + lane) * 8);
#pragma unroll
          for (int mt = 0; mt < 2; ++mt) acc[g][mt] = MFMA16(a[mt], b, acc[g][mt], 0, 0, 0);
        }
      }
#pragma unroll
      for (int mt = 0; mt < 2; ++mt)
#pragma unroll
        for (int r = 0; r < 4; ++r) {
          float dtv = dl[t * 32 + mt * 16 + lg * 4 + r];
          float hdv = h[mt][ntp][r] * __expf(-fmaxf(dtv * wtv[ntp], 0.f));
          float zz = sigm(acc[0][mt][r] + bz[ntp]);
          float rr = sigm(acc[1][mt][r] + br[ntp]);
          float nn = tanh_fast(acc[2][mt][r] + bn[ntp] + rr * acc[3][mt][r]);
          h[mt][ntp][r] = (1.f - zz) * hdv + zz * nn;
        }
    }
  }
  __syncthreads();
#pragma unroll
  for (int mt = 0; mt < 2; ++mt)
#pragma unroll
    for (int nt = 0; nt < 2; ++nt)
#pragma unroll
      for (int r = 0; r < 4; ++r)
        hmain[(size_t)(n0 + mt * 16 + lg * 4 + r) * 256 + wv * 32 + nt * 16 + lr] = h[mt][nt][r];
}

__global__ __launch_bounds__(512) void k_rnn_fused(
    const __bf16* __restrict__ G2, const float* __restrict__ dtc,
    const unsigned char* __restrict__ pU8, const float* __restrict__ wt_c,
    float* __restrict__ hcont, const int* __restrict__ x,
    const int* __restrict__ self_loc, const float* __restrict__ emb,
    const __bf16* __restrict__ pWs, const __bf16* __restrict__ pWe,
    const __bf16* __restrict__ pU, const float* __restrict__ b_rnn,
    const float* __restrict__ wt_m, __bf16* __restrict__ em,
    float* __restrict__ xself, float* __restrict__ hmain) {
  __shared__ __align__(16) char smem[8192 + 122880 + 8192];  // 136 KB union
  if (blockIdx.x < 8)
    cont_body(smem, G2, dtc, pU8, wt_c, hcont, blockIdx.x);
  else
    main_body(smem, x, self_loc, emb, pWs, pWe, pU, b_rnn, wt_m, em, xself, hmain,
              blockIdx.x - 8);
}

// ------------------------------------------------------------------ tail
__global__ __launch_bounds__(256) void k_att(const float* __restrict__ hmain,
                                             const float* __restrict__ xself,
                                             const float* __restrict__ hc,
                                             const float* __restrict__ Wv,
                                             const float* __restrict__ bv,
                                             float* __restrict__ hh,
                                             __bf16* __restrict__ hh_bf) {
  int b = blockIdx.x, tid = threadIdx.x;
  __shared__ float hl[16 * 256];
  __shared__ float aa[16 * 4];
  for (int idx = tid; idx < 4096; idx += 256) hl[idx] = hmain[(size_t)b * SS * HH + idx];
  __syncthreads();
  if (tid < 64) {
    int s = tid >> 2, m = tid & 3;
    float acc = bv[m];
    for (int j = 0; j < 256; ++j)
      acc += hl[s * 256 + j] * Wv[j * 4 + m] + hl[j] * Wv[(256 + j) * 4 + m];
    aa[s * 4 + m] = tanh_fast(acc);
  }
  __syncthreads();
  if (tid < 4) {
    int m = tid;
    float mx = -1e30f;
    for (int s = 0; s < 16; ++s) mx = fmaxf(mx, aa[s * 4 + m]);
    float sum = 0.f;
    for (int s = 0; s < 16; ++s) sum += __expf(aa[s * 4 + m] - mx);
    float inv = 1.f / sum;
    for (int s = 0; s < 16; ++s) aa[s * 4 + m] = __expf(aa[s * 4 + m] - mx) * inv;
  }
  __syncthreads();
  float a0 = 0.f, a1 = 0.f, a2 = 0.f, a3 = 0.f;
  for (int s = 0; s < 16; ++s) {
    float hv = hl[s * 256 + tid];
    a0 = fmaf(aa[s * 4 + 0], hv, a0);
    a1 = fmaf(aa[s * 4 + 1], hv, a1);
    a2 = fmaf(aa[s * 4 + 2], hv, a2);
    a3 = fmaf(aa[s * 4 + 3], hv, a3);
  }
  float* hb = hh + (size_t)b * 1664;
  __bf16* hf = hh_bf + (size_t)b * 1664;
  hb[384 + 0 * 256 + tid] = a0;
  hb[384 + 1 * 256 + tid] = a1;
  hb[384 + 2 * 256 + tid] = a2;
  hb[384 + 3 * 256 + tid] = a3;
  hf[384 + 0 * 256 + tid] = (__bf16)a0;
  hf[384 + 1 * 256 + tid] = (__bf16)a1;
  hf[384 + 2 * 256 + tid] = (__bf16)a2;
  hf[384 + 3 * 256 + tid] = (__bf16)a3;
  if (tid < 128) {
    hb[tid] = xself[b * DD + tid];
    hf[tid] = (__bf16)xself[b * DD + tid];
  }
  hb[128 + tid] = hl[tid];
  hf[128 + tid] = (__bf16)hl[tid];
  float hcv = hc[(size_t)b * HH + tid];
  hb[1408 + tid] = hcv;
  hf[1408 + tid] = (__bf16)hcv;
}

// MFMA MLP layer: C = leakyrelu(A @ W + b)
__global__ __launch_bounds__(512) void k_mlp_mfma(const __bf16* __restrict__ A,
                                                  const __bf16* __restrict__ pW,
                                                  const float* __restrict__ bias,
                                                  __bf16* __restrict__ C, int K, int N) {
  const int wv = threadIdx.x >> 6, lane = threadIdx.x & 63;
  const int lr = lane & 15, lg = lane >> 4;
  const int r0 = blockIdx.y * 32;
  const int c0 = blockIdx.x * 256;
  const int NT = N >> 4;
  const int KT = K >> 5;
  f32x4 acc[2][2];
#pragma unroll
  for (int mt = 0; mt < 2; ++mt)
#pragma unroll
    for (int nt = 0; nt < 2; ++nt) acc[mt][nt] = f32x4{0.f, 0.f, 0.f, 0.f};
  for (int kt = 0; kt < KT; ++kt) {
    bf16x8 a[2];
#pragma unroll
    for (int mt = 0; mt < 2; ++mt)
      a[mt] = *(const bf16x8*)(A + (size_t)(r0 + mt * 16 + lr) * K + kt * 32 + lg * 8);
#pragma unroll
    for (int nt = 0; nt < 2; ++nt) {
      bf16x8 b = *(const bf16x8*)(pW + (((size_t)kt * NT + (c0 >> 4) + wv * 2 + nt) * 64 + lane) * 8);
#pragma unroll
      for (int mt = 0; mt < 2; ++mt) acc[mt][nt] = MFMA16(a[mt], b, acc[mt][nt], 0, 0, 0);
    }
  }
#pragma unroll
  for (int nt = 0; nt < 2; ++nt) {
    int col = c0 + wv * 32 + nt * 16 + lr;
    float bc = bias[col];
#pragma unroll
    for (int mt = 0; mt < 2; ++mt)
#pragma unroll
      for (int r = 0; r < 4; ++r) {
        float v = acc[mt][nt][r] + bc;
        v = v > 0.f ? v : 0.01f * v;
        C[(size_t)(r0 + mt * 16 + lg * 4 + r) * N + col] = (__bf16)v;
      }
  }
}

__global__ __launch_bounds__(64) void k_head(const __bf16* __restrict__ A,
                                             const float* __restrict__ Wp,
                                             const float* __restrict__ bp,
                                             float* __restrict__ out) {
  int row = blockIdx.x, l = threadIdx.x;
  float acc = 0.f;
  for (int j = l; j < 256; j += 64) acc = fmaf((float)A[(size_t)row * 256 + j], Wp[j], acc);
  for (int o = 32; o; o >>= 1) acc += __shfl_xor(acc, o);
  if (l == 0) out[row] = 1.f / (1.f + __expf(-(acc + bp[0])));
}

extern "C" void kernel_launch(void* const* d_in, const int* in_sizes, int n_in,
                              void* d_out, int out_size, void* d_ws, size_t ws_size,
                              hipStream_t stream) {
  const int* x = (const int*)d_in[0];
  const int* xc = (const int*)d_in[1];
  const int* self_loc = (const int*)d_in[2];
  const float* emb = (const float*)d_in[3];
  const float* W_rnn = (const float*)d_in[4];
  const float* U_rnn = (const float*)d_in[5];
  const float* b_rnn = (const float*)d_in[6];
  const float* wt_rnn = (const float*)d_in[7];
  const float* W_c = (const float*)d_in[8];
  const float* U_c = (const float*)d_in[9];
  const float* b_c = (const float*)d_in[10];
  const float* wt_c = (const float*)d_in[11];
  const float* Wv = (const float*)d_in[12];
  const float* bv = (const float*)d_in[13];
  const float* W0 = (const float*)d_in[14];
  const float* b0 = (const float*)d_in[15];
  const float* W1 = (const float*)d_in[16];
  const float* b1 = (const float*)d_in[17];
  const float* W2 = (const float*)d_in[18];
  const float* b2 = (const float*)d_in[19];
  const float* Wp = (const float*)d_in[20];
  const float* bp = (const float*)d_in[21];
  float* out = (float*)d_out;

  char* ws = (char*)d_ws;
  size_t cur = 0;
  auto alloc = [&](size_t bytes) {
    char* p = ws + cur;
    cur += (bytes + 255) & ~(size_t)255;
    return p;
  };
  float* xself = (float*)alloc((size_t)BB * DD * 4);
  float* dtc = (float*)alloc((size_t)128 * 128 * 4);
  float* hcont = (float*)alloc((size_t)BB * HH * 4);
  float* hh = (float*)alloc((size_t)BB * 1664 * 4);
  __bf16* hh_bf = (__bf16*)alloc((size_t)BB * 1664 * 2);
  __bf16* z0 = (__bf16*)alloc((size_t)BB * 1024 * 2);
  __bf16* z1 = (__bf16*)alloc((size_t)BB * 512 * 2);
  __bf16* z2 = (__bf16*)alloc((size_t)BB * 256 * 2);
  float* hmain = (float*)alloc((size_t)8192 * HH * 4);
  __hip_bfloat16* ec = (__hip_bfloat16*)alloc((size_t)16384 * DD * 2);
  __bf16* em = (__bf16*)alloc((size_t)KK * 8192 * DD * 2);
  __bf16* G2 = (__bf16*)alloc((size_t)16384 * 1024 * 2);
  __bf16* pWs = (__bf16*)alloc((size_t)4 * 48 * 64 * 8 * 2);
  __bf16* pWe = (__bf16*)alloc((size_t)4 * 48 * 64 * 8 * 2);
  __bf16* pU = (__bf16*)alloc((size_t)8 * 48 * 64 * 8 * 2);
  __bf16* pWc = (__bf16*)alloc((size_t)4 * 48 * 64 * 8 * 2);
  unsigned char* pU8 = (unsigned char*)alloc((size_t)8 * 48 * 64 * 8);
  __bf16* pW0 = (__bf16*)alloc((size_t)52 * 64 * 64 * 8 * 2);
  __bf16* pW1 = (__bf16*)alloc((size_t)32 * 32 * 64 * 8 * 2);
  __bf16* pW2 = (__bf16*)alloc((size_t)16 * 16 * 64 * 8 * 2);
  (void)ws_size;

  hipLaunchKernelGGL(k_build_cont, dim3(128, 128), dim3(128), 0, stream, xc, emb, ec, dtc);
  hipLaunchKernelGGL(k_pack, dim3(4, 48), dim3(64), 0, stream, W_c, pWc);
  hipLaunchKernelGGL(k_pack8, dim3(8, 48), dim3(64), 0, stream, U_c, pU8);
  hipLaunchKernelGGL(k_gemm_g, dim3(512), dim3(512), 0, stream, ec, pWc, b_c, G2);
  hipLaunchKernelGGL(k_pack, dim3(4, 48), dim3(64), 0, stream, W_rnn, pWs);
  hipLaunchKernelGGL(k_pack, dim3(4, 48), dim3(64), 0, stream, W_rnn + 128 * 768, pWe);
  hipLaunchKernelGGL(k_pack, dim3(8, 48), dim3(64), 0, stream, U_rnn, pU);
  hipLaunchKernelGGL(k_packN, dim3(52, 64), dim3(64), 0, stream, W0, pW0, 1024);
  hipLaunchKernelGGL(k_packN, dim3(32, 32), dim3(64), 0, stream, W1, pW1, 512);
  hipLaunchKernelGGL(k_packN, dim3(16, 16), dim3(64), 0, stream, W2, pW2, 256);
  hipLaunchKernelGGL(k_rnn_fused, dim3(264), dim3(512), 0, stream, G2, dtc, pU8, wt_c,
                     hcont, x, self_loc, emb, pWs, pWe, pU, b_rnn, wt_rnn, em, xself,
                     hmain);
  hipLaunchKernelGGL(k_att, dim3(BB), dim3(256), 0, stream, hmain, xself, hcont, Wv, bv, hh,
                     hh_bf);
  hipLaunchKernelGGL(k_mlp_mfma, dim3(4, 16), dim3(512), 0, stream, hh_bf, pW0, b0, z0,
                     1664, 1024);
  hipLaunchKernelGGL(k_mlp_mfma, dim3(2, 16), dim3(512), 0, stream, z0, pW1, b1, z1, 1024,
                     512);
  hipLaunchKernelGGL(k_mlp_mfma, dim3(1, 16), dim3(512), 0, stream, z1, pW2, b2, z2, 512,
                     256);
  hipLaunchKernelGGL(k_head, dim3(BB), dim3(64), 0, stream, z2, Wp, bp, out);
}

// Round 20
// 764.053 us; speedup vs baseline: 1.3084x; 1.0026x over previous
//
#include <hip/hip_runtime.h>
#include <hip/hip_bf16.h>

// SearchPredictModel round 20: R19 + cont G2 double-buffered prefetch
// (issue t+1's G loads after the ds_write of step t -> slack grows from
// ~1 MFMA ladder to ~1 full step; G exposure under main-block L2 traffic
// was the best-supported residual latency in cont's 97%-stall step).

#define PAD_TOK 200000
#define DD 128
#define HH 256
#define KK 15
#define BB 512
#define SS 16
#define II 64

typedef __bf16 bf16x8 __attribute__((ext_vector_type(8)));
typedef __bf16 bf16x4 __attribute__((ext_vector_type(4)));
typedef float f32x4 __attribute__((ext_vector_type(4)));
#define MFMA16 __builtin_amdgcn_mfma_f32_16x16x32_bf16
#define MFMA8 __builtin_amdgcn_mfma_f32_16x16x32_fp8_fp8

__device__ __forceinline__ float sigm(float x) { return 1.f / (1.f + __expf(-x)); }
__device__ __forceinline__ float tanh_fast(float x) {
  x = fminf(fmaxf(x, -15.f), 15.f);
  float e2 = __expf(2.f * x);
  return (e2 - 1.f) / (e2 + 1.f);
}
__device__ __forceinline__ float bfu(unsigned u16) { return __uint_as_float(u16 << 16); }

// float -> fp8 e4m3 (OCP), RNE, FTZ below 2^-6 (software fallback)
__device__ __forceinline__ unsigned char f2fp8(float x) {
  unsigned u = __float_as_uint(x);
  unsigned s = (u >> 31) << 7;
  int e = (int)((u >> 23) & 0xff) - 127;
  if (e < -6) return (unsigned char)s;
  unsigned m = (u >> 20) & 7;
  unsigned rest = u & 0xFFFFF;
  if (rest > 0x80000 || (rest == 0x80000 && (m & 1))) {
    ++m;
    if (m == 8) {
      m = 0;
      ++e;
    }
  }
  if (e > 7) {
    e = 7;
    m = 6;
  }
  return (unsigned char)(s | ((unsigned)(e + 7) << 3) | m);
}

__device__ __forceinline__ unsigned cvt2fp8(float a, float b) {
#if __has_builtin(__builtin_amdgcn_cvt_pk_fp8_f32)
  return (unsigned)__builtin_amdgcn_cvt_pk_fp8_f32(a, b, 0, false) & 0xffffu;
#else
  return (unsigned)f2fp8(a) | ((unsigned)f2fp8(b) << 8);
#endif
}

// ---------------------------------------------------------------- front end
__global__ __launch_bounds__(128) void k_build_cont(const int* __restrict__ xc,
                                                    const float* __restrict__ emb,
                                                    __hip_bfloat16* __restrict__ ec,
                                                    float* __restrict__ dtc) {
  int p = blockIdx.x, t = blockIdx.y, d = threadIdx.x;
  const int* xr = xc + ((size_t)p * 128 + t) * 8;
  float acc = 0.f;
#pragma unroll
  for (int jj = 0; jj < 6; ++jj) acc += emb[(size_t)xr[jj] * DD + d];
  ec[((size_t)p * 128 + t) * DD + d] = __float2bfloat16(acc);
  if (d == 0) dtc[p * 128 + t] = (t > 0) ? ((float)xr[6] - (float)xr[-2]) : 0.f;
}

// ------------------------------------------------- weight fragment packing
__global__ __launch_bounds__(64) void k_pack(const float* __restrict__ B,
                                             __bf16* __restrict__ out) {
  int kt = blockIdx.x, tile = blockIdx.y, lane = threadIdx.x;
  const float* src = B + (size_t)(kt * 32 + (lane >> 4) * 8) * 768 + tile * 16 + (lane & 15);
  __bf16* o = out + (((size_t)(kt * 48 + tile) * 64 + lane) * 8);
#pragma unroll
  for (int i = 0; i < 8; ++i) o[i] = (__bf16)src[(size_t)i * 768];
}

// U_c -> fp8 fragments (x8 scale)
__global__ __launch_bounds__(64) void k_pack8(const float* __restrict__ B,
                                              unsigned char* __restrict__ out) {
  int kt = blockIdx.x, tile = blockIdx.y, lane = threadIdx.x;
  const float* src = B + (size_t)(kt * 32 + (lane >> 4) * 8) * 768 + tile * 16 + (lane & 15);
  unsigned char* o = out + (((size_t)(kt * 48 + tile) * 64 + lane) * 8);
#pragma unroll
  for (int i = 0; i < 8; ++i) o[i] = f2fp8(src[(size_t)i * 768] * 8.f);
}

// general pack for [K x N] f32 -> MFMA fragments
__global__ __launch_bounds__(64) void k_packN(const float* __restrict__ B,
                                              __bf16* __restrict__ out, int N) {
  int kt = blockIdx.x, tile = blockIdx.y, lane = threadIdx.x;
  const float* src = B + (size_t)(kt * 32 + (lane >> 4) * 8) * N + tile * 16 + (lane & 15);
  __bf16* o = out + (((size_t)kt * gridDim.y + tile) * 64 + lane) * 8;
#pragma unroll
  for (int i = 0; i < 8; ++i) o[i] = (__bf16)src[(size_t)i * N];
}

// -------- cont-RNN g precompute: G2 (fragment-packed) = ec@Wc + b
__global__ __launch_bounds__(512) void k_gemm_g(const __hip_bfloat16* __restrict__ A,
                                                const __bf16* __restrict__ pB,
                                                const float* __restrict__ bias,
                                                __bf16* __restrict__ G2) {
  const int wv = threadIdx.x >> 6, lane = threadIdx.x & 63;
  const int lr = lane & 15, lg = lane >> 4;
  const int r0 = blockIdx.x * 32;
  f32x4 z4 = {0.f, 0.f, 0.f, 0.f};
  f32x4 acc[2][6];
#pragma unroll
  for (int mt = 0; mt < 2; ++mt)
#pragma unroll
    for (int n = 0; n < 6; ++n) acc[mt][n] = z4;
#pragma unroll
  for (int kt = 0; kt < 4; ++kt) {
    bf16x8 a[2];
#pragma unroll
    for (int mt = 0; mt < 2; ++mt)
      a[mt] = *(const bf16x8*)(A + (size_t)(r0 + mt * 16 + lr) * 128 + kt * 32 + lg * 8);
#pragma unroll
    for (int n = 0; n < 6; ++n) {
      bf16x8 b = *(const bf16x8*)(pB + (((size_t)kt * 48 + wv * 6 + n) * 64 + lane) * 8);
      acc[0][n] = MFMA16(a[0], b, acc[0][n], 0, 0, 0);
      acc[1][n] = MFMA16(a[1], b, acc[1][n], 0, 0, 0);
    }
  }
#pragma unroll
  for (int mt = 0; mt < 2; ++mt)
#pragma unroll
    for (int n = 0; n < 6; ++n) {
      int col = wv * 96 + n * 16 + lr;
      int gate = col >> 8, wvc = (col >> 5) & 7, nt = (col >> 4) & 1;
      float bc = bias[col];
#pragma unroll
      for (int r = 0; r < 4; ++r) {
        int row = r0 + mt * 16 + lg * 4 + r;
        G2[(size_t)row * 1024 + wvc * 128 + lr * 8 + gate * 2 + nt] = (__bf16)(acc[mt][n][r] + bc);
      }
    }
}

// ------------------------------------------------------ fused RNN kernel
__device__ void cont_body(char* smem, const __bf16* __restrict__ G2,
                          const float* __restrict__ dtc,
                          const unsigned char* __restrict__ pU8,
                          const float* __restrict__ wt, float* __restrict__ hcont,
                          int blk) {
  unsigned char(*hbuf)[16 * 256] = (unsigned char(*)[16 * 256])smem;  // 8 KB
  unsigned char(*uL)[30 * 512] = (unsigned char(*)[30 * 512])(smem + 8192);  // 120 KB
  float* dl = (float*)(smem + 8192 + 122880);                                // 8 KB
  const int wv = threadIdx.x >> 6, lane = threadIdx.x & 63;
  const int lr = lane & 15, lg = lane >> 4;
  const int p0 = blk * 16;
  for (int idx = threadIdx.x; idx < 2048; idx += 512)
    dl[idx] = dtc[(p0 + (idx >> 7)) * 128 + (idx & 127)];
  for (int i = threadIdx.x; i < 8 * 30 * 64; i += 512) {
    int l = i & 63;
    int fw = i >> 6;
    int f = fw % 30;
    int w = fw / 30;
    int kt = 3 + f / 6;
    int gi = f % 6;
    *(uint2*)&uL[w][(size_t)f * 512 + l * 8] =
        *(const uint2*)(pU8 + (((size_t)kt * 48 + (gi >> 1) * 16 + w * 2 + (gi & 1)) * 64 + l) * 8);
  }
  long fr[3][6];
#pragma unroll
  for (int kt = 0; kt < 3; ++kt)
#pragma unroll
    for (int gi = 0; gi < 6; ++gi)
      fr[kt][gi] =
          *(const long*)(pU8 + (((size_t)kt * 48 + (gi >> 1) * 16 + wv * 2 + (gi & 1)) * 64 + lane) * 8);

  float wtv[2];
#pragma unroll
  for (int nt = 0; nt < 2; ++nt) wtv[nt] = wt[wv * 32 + nt * 16 + lr];
  float h[2][4];
#pragma unroll
  for (int nt = 0; nt < 2; ++nt)
#pragma unroll
    for (int r = 0; r < 4; ++r) h[nt][r] = 0.f;

  const uint4* G2v = (const uint4*)G2;
  const size_t gb0 = (size_t)(p0 + lg * 4) * 16384 + wv * 16 + lr;
  // prologue: load t=0 G values
  uint4 Gv[4], Gn[4];
#pragma unroll
  for (int r = 0; r < 4; ++r) Gv[r] = G2v[gb0 + (size_t)r * 16384];
  __syncthreads();

  for (int t = 0; t < 128; ++t) {
    unsigned char* hb = hbuf[t & 1];
    float hd[2][4];
#pragma unroll
    for (int r = 0; r < 4; ++r) {
      float dtv = dl[(lg * 4 + r) * 128 + t];
#pragma unroll
      for (int nt = 0; nt < 2; ++nt) hd[nt][r] = h[nt][r] * __expf(-fmaxf(dtv * wtv[nt], 0.f));
    }
    const int c0 = wv * 32 + lr, c1 = wv * 32 + 16 + lr;
#pragma unroll
    for (int r = 0; r < 4; ++r) {
      int row = lg * 4 + r;
      int sw = (row & 15) << 3;
      unsigned pk = cvt2fp8(hd[0][r] * 16.f, hd[1][r] * 16.f);
      hb[row * 256 + (c0 ^ sw)] = (unsigned char)pk;
      hb[row * 256 + (c1 ^ sw)] = (unsigned char)(pk >> 8);
    }
    // issue NEXT step's G loads here (off the hd->write chain; consumed at
    // t+1's gates -> ~one full step of slack)
    if (t < 127) {
#pragma unroll
      for (int r = 0; r < 4; ++r) Gn[r] = G2v[gb0 + (size_t)r * 16384 + (size_t)(t + 1) * 128];
    }
    __syncthreads();
    f32x4 acc[3][2];
#pragma unroll
    for (int g = 0; g < 3; ++g)
#pragma unroll
      for (int nt = 0; nt < 2; ++nt) acc[g][nt] = f32x4{0.f, 0.f, 0.f, 0.f};
#pragma unroll
    for (int kt = 0; kt < 8; ++kt) {
      long a = *(const long*)&hb[lr * 256 + ((kt * 32 + lg * 8) ^ ((lr & 15) << 3))];
#pragma unroll
      for (int gi = 0; gi < 6; ++gi) {
        long b = (kt < 3) ? fr[kt][gi]
                          : *(const long*)&uL[wv][(size_t)((kt - 3) * 6 + gi) * 512 + lane * 8];
        acc[gi >> 1][gi & 1] = MFMA8(a, b, acc[gi >> 1][gi & 1], 0, 0, 0);
      }
    }
#pragma unroll
    for (int nt = 0; nt < 2; ++nt)
#pragma unroll
      for (int r = 0; r < 4; ++r) {
        unsigned uz = nt ? (Gv[r].x >> 16) : (Gv[r].x & 0xffffu);
        unsigned ur = nt ? (Gv[r].y >> 16) : (Gv[r].y & 0xffffu);
        unsigned un = nt ? (Gv[r].z >> 16) : (Gv[r].z & 0xffffu);
        const float us = 0.0078125f;  // 1/(16*8)
        float zz = sigm(bfu(uz) + acc[0][nt][r] * us);
        float rr = sigm(bfu(ur) + acc[1][nt][r] * us);
        float nn = tanh_fast(bfu(un) + rr * acc[2][nt][r] * us);
        float hnew = (1.f - zz) * hd[nt][r] + zz * nn;
        h[nt][r] = hnew;
        if (t >= 124)
          hcont[((size_t)(p0 + lg * 4 + r) * 4 + (t - 124)) * 256 + wv * 32 + nt * 16 + lr] = hnew;
      }
#pragma unroll
    for (int r = 0; r < 4; ++r) Gv[r] = Gn[r];
  }
}

// main: phase 0 = eself/cos/topk/build (block-local); phase 2 = recurrence.
__device__ void main_body(char* smem, const int* __restrict__ x,
                          const int* __restrict__ self_loc,
                          const float* __restrict__ emb,
                          const __bf16* __restrict__ pWs, const __bf16* __restrict__ pWe,
                          const __bf16* __restrict__ pU, const float* __restrict__ bg,
                          const float* __restrict__ wt, __bf16* __restrict__ em,
                          float* __restrict__ xself, float* __restrict__ hmain,
                          int blk) {
  __bf16(*hbuf)[32 * 256] = (__bf16(*)[32 * 256])smem;  // 2 x 16KB
  float* dl = (float*)(smem + 32768);                   // KK*32 f32 (1920B)
  float* esL = (float*)(smem + 34944);                  // 2*128 f32
  float* nsL = (float*)(smem + 35968);                  // 2 f32
  __bf16* xsbf = (__bf16*)(smem + 36000);               // 2*128 bf16 (512B)
  float* simL = (float*)(smem + 36544);                 // 32*64 f32 (8KB)
  int* tpxL = (int*)(smem + 44736);                     // 32*15 int (1920B)
  const int tid = threadIdx.x;
  const int wv = tid >> 6, lane = tid & 63;
  const int lr = lane & 15, lg = lane >> 4;
  const int n0 = blk * 32;
  const int b0 = n0 >> 4;
  f32x4 z4 = {0.f, 0.f, 0.f, 0.f};

  // ---- phase 0a: e_self + norms for the block's 2 b-groups
  if (tid < 256) {
    int bb = tid >> 7, d = tid & 127;
    int bgl = b0 + bb;
    int tok = x[((size_t)(bgl * SS) * II + self_loc[bgl]) * 8 + 5];
    esL[bb * 128 + d] = emb[(size_t)tok * DD + d];
  }
  __syncthreads();
  if (tid < 128) {
    int bb = tid >> 6, l = tid & 63;
    float v0 = esL[bb * 128 + l], v1 = esL[bb * 128 + 64 + l];
    float ss = v0 * v0 + v1 * v1;
    for (int o = 32; o; o >>= 1) ss += __shfl_xor(ss, o);
    if (l == 0) nsL[bb] = fmaxf(sqrtf(ss), 1e-8f);
  }
  __syncthreads();
  // ---- phase 0b: cos -> sim (4 lanes per (row,item)); neg fill = -3
  for (int it = 0; it < 16; ++it) {
    int pr = it * 128 + (tid >> 2);
    int row = pr >> 6, item = pr & 63, q = tid & 3;
    const int* xr = x + ((size_t)(n0 + row) * II + item) * 8;
    int tok = xr[5];
    int first = xr[0];
    const float4* ep = (const float4*)(emb + (size_t)tok * DD + q * 32);
    const float4* sp = (const float4*)(esL + (row >> 4) * 128 + q * 32);
    float dot = 0.f, ss = 0.f;
#pragma unroll
    for (int j = 0; j < 8; ++j) {
      float4 a = ep[j];
      float4 e = sp[j];
      dot += a.x * e.x + a.y * e.y + a.z * e.z + a.w * e.w;
      ss += a.x * a.x + a.y * a.y + a.z * a.z + a.w * a.w;
    }
    dot += __shfl_xor(dot, 1);
    ss += __shfl_xor(ss, 1);
    dot += __shfl_xor(dot, 2);
    ss += __shfl_xor(ss, 2);
    if (q == 0)
      simL[row * 64 + item] =
          (first != PAD_TOK) ? dot / (fmaxf(sqrtf(ss), 1e-8f) * nsL[row >> 4]) : -3.0f;
  }
  __syncthreads();
  // ---- phase 0c: top-K, ASCENDING-INDEX order via ballot compaction
  for (int it = 0; it < 4; ++it) {
    int pr = it * 512 + tid;
    int row = pr >> 6, item = pr & 63;
    float s = simL[row * 64 + item];
    int rank = 0;
    for (int j = 0; j < 64; ++j) {
      float o = simL[row * 64 + j];
      rank += (o > s) || (o == s && j < item);
    }
    bool sel = rank < KK;
    unsigned long long mask = __ballot(sel);
    if (sel) {
      int pos = __popcll(mask & ((1ull << item) - 1ull));
      tpxL[row * KK + pos] = item;
    }
  }
  __syncthreads();
  // ---- phase 0d: gather/sum -> em (global, block rows), dl, xself
  for (int t = 0; t < KK; ++t) {
    int rr = tid >> 5, q = tid & 31;
#pragma unroll
    for (int pass = 0; pass < 2; ++pass) {
      int rloc = pass * 16 + rr;
      int ng = n0 + rloc;
      int bb = ng >> 4, s = ng & 15;
      bool ovr = (s == 0) && (t == KK - 1);
      int item = ovr ? self_loc[bb] : tpxL[rloc * KK + t];
      const int* xr = x + ((size_t)ng * II + item) * 8;
      float4 a4 = {0.f, 0.f, 0.f, 0.f};
#pragma unroll
      for (int jj = 0; jj < 6; ++jj) {
        float4 v = *(const float4*)(emb + (size_t)xr[jj] * DD + q * 4);
        a4.x += v.x;
        a4.y += v.y;
        a4.z += v.z;
        a4.w += v.w;
      }
      bf16x4 ov = {(__bf16)a4.x, (__bf16)a4.y, (__bf16)a4.z, (__bf16)a4.w};
      *(bf16x4*)(em + ((size_t)t * 8192 + ng) * DD + q * 4) = ov;
      if (ovr) {
        *(float4*)(xself + bb * DD + q * 4) = a4;
        *(bf16x4*)(xsbf + (bb - b0) * 128 + q * 4) = ov;
      }
      if (q == 0) {
        float dtv = 0.f;
        if (t > 0) {
          int pitem = tpxL[rloc * KK + t - 1];
          dtv = (float)xr[6] - (float)x[((size_t)ng * II + pitem) * 8 + 6];
        }
        dl[t * 32 + rloc] = dtv;
      }
    }
  }
  __syncthreads();

  // ---- phase 2: recurrence (R17 nt-split, no spill)
  float wtv[2], bz[2], br[2], bn[2];
#pragma unroll
  for (int nt = 0; nt < 2; ++nt) {
    int c = wv * 32 + nt * 16 + lr;
    wtv[nt] = wt[c];
    bz[nt] = bg[c];
    br[nt] = bg[c + 256];
    bn[nt] = bg[c + 512];
  }
  float h[2][2][4];
#pragma unroll
  for (int mt = 0; mt < 2; ++mt)
#pragma unroll
    for (int nt = 0; nt < 2; ++nt)
#pragma unroll
      for (int r = 0; r < 4; ++r) h[mt][nt][r] = 0.f;

  for (int t = 0; t < KK; ++t) {
    __bf16* hb = hbuf[t & 1];
#pragma unroll
    for (int mt = 0; mt < 2; ++mt)
#pragma unroll
      for (int r = 0; r < 4; ++r) {
        float dtv = dl[t * 32 + mt * 16 + lg * 4 + r];
        int row = mt * 16 + lg * 4 + r;
#pragma unroll
        for (int nt = 0; nt < 2; ++nt) {
          float hdv = h[mt][nt][r] * __expf(-fmaxf(dtv * wtv[nt], 0.f));
          hb[((row * 256) + (wv * 32 + nt * 16 + lr)) ^ ((row & 7) << 3)] = (__bf16)hdv;
        }
      }
    __syncthreads();
#pragma unroll
    for (int ntp = 0; ntp < 2; ++ntp) {
      f32x4 acc[4][2];
#pragma unroll
      for (int a4 = 0; a4 < 4; ++a4)
#pragma unroll
        for (int mt = 0; mt < 2; ++mt) acc[a4][mt] = z4;
#pragma unroll 2
      for (int kt = 0; kt < 8; ++kt) {
        bf16x8 a[2];
#pragma unroll
        for (int mt = 0; mt < 2; ++mt) {
          int row = mt * 16 + lr;
          int s = ((row * 256) + (kt * 32 + lg * 8)) ^ ((row & 7) << 3);
          a[mt] = *(const bf16x8*)&hb[s];
        }
#pragma unroll
        for (int g = 0; g < 3; ++g) {
          const int ai = (g < 2) ? g : 3;
          bf16x8 b = *(const bf16x8*)(pU + (((size_t)kt * 48 + g * 16 + wv * 2 + ntp) * 64 + lane) * 8);
#pragma unroll
          for (int mt = 0; mt < 2; ++mt) acc[ai][mt] = MFMA16(a[mt], b, acc[ai][mt], 0, 0, 0);
        }
      }
#pragma unroll 2
      for (int kt = 0; kt < 8; ++kt) {
        bf16x8 a[2];
#pragma unroll
        for (int mt = 0; mt < 2; ++mt) {
          if (kt < 4)
            a[mt] = *(const bf16x8*)(xsbf + mt * 128 + kt * 32 + lg * 8);
          else
            a[mt] = *(const bf16x8*)(em + ((size_t)t * 8192 + n0 + mt * 16 + lr) * 128 +
                                     (kt - 4) * 32 + lg * 8);
        }
        const __bf16* pB = (kt < 4) ? (pWs + (size_t)kt * 48 * 512)
                                    : (pWe + (size_t)(kt - 4) * 48 * 512);
#pragma unroll
        for (int g = 0; g < 3; ++g) {
          bf16x8 b = *(const bf16x8*)(pB + (((size_t)g * 16 + wv * 2 + ntp) * 64 + lane) * 8);
#pragma unroll
          for (int mt = 0; mt < 2; ++mt) acc[g][mt] = MFMA16(a[mt], b, acc[g][mt], 0, 0, 0);
        }
      }
#pragma unroll
      for (int mt = 0; mt < 2; ++mt)
#pragma unroll
        for (int r = 0; r < 4; ++r) {
          float dtv = dl[t * 32 + mt * 16 + lg * 4 + r];
          float hdv = h[mt][ntp][r] * __expf(-fmaxf(dtv * wtv[ntp], 0.f));
          float zz = sigm(acc[0][mt][r] + bz[ntp]);
          float rr = sigm(acc[1][mt][r] + br[ntp]);
          float nn = tanh_fast(acc[2][mt][r] + bn[ntp] + rr * acc[3][mt][r]);
          h[mt][ntp][r] = (1.f - zz) * hdv + zz * nn;
        }
    }
  }
  __syncthreads();
#pragma unroll
  for (int mt = 0; mt < 2; ++mt)
#pragma unroll
    for (int nt = 0; nt < 2; ++nt)
#pragma unroll
      for (int r = 0; r < 4; ++r)
        hmain[(size_t)(n0 + mt * 16 + lg * 4 + r) * 256 + wv * 32 + nt * 16 + lr] = h[mt][nt][r];
}

__global__ __launch_bounds__(512) void k_rnn_fused(
    const __bf16* __restrict__ G2, const float* __restrict__ dtc,
    const unsigned char* __restrict__ pU8, const float* __restrict__ wt_c,
    float* __restrict__ hcont, const int* __restrict__ x,
    const int* __restrict__ self_loc, const float* __restrict__ emb,
    const __bf16* __restrict__ pWs, const __bf16* __restrict__ pWe,
    const __bf16* __restrict__ pU, const float* __restrict__ b_rnn,
    const float* __restrict__ wt_m, __bf16* __restrict__ em,
    float* __restrict__ xself, float* __restrict__ hmain) {
  __shared__ __align__(16) char smem[8192 + 122880 + 8192];  // 136 KB union
  if (blockIdx.x < 8)
    cont_body(smem, G2, dtc, pU8, wt_c, hcont, blockIdx.x);
  else
    main_body(smem, x, self_loc, emb, pWs, pWe, pU, b_rnn, wt_m, em, xself, hmain,
              blockIdx.x - 8);
}

// ------------------------------------------------------------------ tail
__global__ __launch_bounds__(256) void k_att(const float* __restrict__ hmain,
                                             const float* __restrict__ xself,
                                             const float* __restrict__ hc,
                                             const float* __restrict__ Wv,
                                             const float* __restrict__ bv,
                                             float* __restrict__ hh,
                                             __bf16* __restrict__ hh_bf) {
  int b = blockIdx.x, tid = threadIdx.x;
  __shared__ float hl[16 * 256];
  __shared__ float aa[16 * 4];
  for (int idx = tid; idx < 4096; idx += 256) hl[idx] = hmain[(size_t)b * SS * HH + idx];
  __syncthreads();
  if (tid < 64) {
    int s = tid >> 2, m = tid & 3;
    float acc = bv[m];
    for (int j = 0; j < 256; ++j)
      acc += hl[s * 256 + j] * Wv[j * 4 + m] + hl[j] * Wv[(256 + j) * 4 + m];
    aa[s * 4 + m] = tanh_fast(acc);
  }
  __syncthreads();
  if (tid < 4) {
    int m = tid;
    float mx = -1e30f;
    for (int s = 0; s < 16; ++s) mx = fmaxf(mx, aa[s * 4 + m]);
    float sum = 0.f;
    for (int s = 0; s < 16; ++s) sum += __expf(aa[s * 4 + m] - mx);
    float inv = 1.f / sum;
    for (int s = 0; s < 16; ++s) aa[s * 4 + m] = __expf(aa[s * 4 + m] - mx) * inv;
  }
  __syncthreads();
  float a0 = 0.f, a1 = 0.f, a2 = 0.f, a3 = 0.f;
  for (int s = 0; s < 16; ++s) {
    float hv = hl[s * 256 + tid];
    a0 = fmaf(aa[s * 4 + 0], hv, a0);
    a1 = fmaf(aa[s * 4 + 1], hv, a1);
    a2 = fmaf(aa[s * 4 + 2], hv, a2);
    a3 = fmaf(aa[s * 4 + 3], hv, a3);
  }
  float* hb = hh + (size_t)b * 1664;
  __bf16* hf = hh_bf + (size_t)b * 1664;
  hb[384 + 0 * 256 + tid] = a0;
  hb[384 + 1 * 256 + tid] = a1;
  hb[384 + 2 * 256 + tid] = a2;
  hb[384 + 3 * 256 + tid] = a3;
  hf[384 + 0 * 256 + tid] = (__bf16)a0;
  hf[384 + 1 * 256 + tid] = (__bf16)a1;
  hf[384 + 2 * 256 + tid] = (__bf16)a2;
  hf[384 + 3 * 256 + tid] = (__bf16)a3;
  if (tid < 128) {
    hb[tid] = xself[b * DD + tid];
    hf[tid] = (__bf16)xself[b * DD + tid];
  }
  hb[128 + tid] = hl[tid];
  hf[128 + tid] = (__bf16)hl[tid];
  float hcv = hc[(size_t)b * HH + tid];
  hb[1408 + tid] = hcv;
  hf[1408 + tid] = (__bf16)hcv;
}

// MFMA MLP layer: C = leakyrelu(A @ W + b)
__global__ __launch_bounds__(512) void k_mlp_mfma(const __bf16* __restrict__ A,
                                                  const __bf16* __restrict__ pW,
                                                  const float* __restrict__ bias,
                                                  __bf16* __restrict__ C, int K, int N) {
  const int wv = threadIdx.x >> 6, lane = threadIdx.x & 63;
  const int lr = lane & 15, lg = lane >> 4;
  const int r0 = blockIdx.y * 32;
  const int c0 = blockIdx.x * 256;
  const int NT = N >> 4;
  const int KT = K >> 5;
  f32x4 acc[2][2];
#pragma unroll
  for (int mt = 0; mt < 2; ++mt)
#pragma unroll
    for (int nt = 0; nt < 2; ++nt) acc[mt][nt] = f32x4{0.f, 0.f, 0.f, 0.f};
  for (int kt = 0; kt < KT; ++kt) {
    bf16x8 a[2];
#pragma unroll
    for (int mt = 0; mt < 2; ++mt)
      a[mt] = *(const bf16x8*)(A + (size_t)(r0 + mt * 16 + lr) * K + kt * 32 + lg * 8);
#pragma unroll
    for (int nt = 0; nt < 2; ++nt) {
      bf16x8 b = *(const bf16x8*)(pW + (((size_t)kt * NT + (c0 >> 4) + wv * 2 + nt) * 64 + lane) * 8);
#pragma unroll
      for (int mt = 0; mt < 2; ++mt) acc[mt][nt] = MFMA16(a[mt], b, acc[mt][nt], 0, 0, 0);
    }
  }
#pragma unroll
  for (int nt = 0; nt < 2; ++nt) {
    int col = c0 + wv * 32 + nt * 16 + lr;
    float bc = bias[col];
#pragma unroll
    for (int mt = 0; mt < 2; ++mt)
#pragma unroll
      for (int r = 0; r < 4; ++r) {
        float v = acc[mt][nt][r] + bc;
        v = v > 0.f ? v : 0.01f * v;
        C[(size_t)(r0 + mt * 16 + lg * 4 + r) * N + col] = (__bf16)v;
      }
  }
}

__global__ __launch_bounds__(64) void k_head(const __bf16* __restrict__ A,
                                             const float* __restrict__ Wp,
                                             const float* __restrict__ bp,
                                             float* __restrict__ out) {
  int row = blockIdx.x, l = threadIdx.x;
  float acc = 0.f;
  for (int j = l; j < 256; j += 64) acc = fmaf((float)A[(size_t)row * 256 + j], Wp[j], acc);
  for (int o = 32; o; o >>= 1) acc += __shfl_xor(acc, o);
  if (l == 0) out[row] = 1.f / (1.f + __expf(-(acc + bp[0])));
}

extern "C" void kernel_launch(void* const* d_in, const int* in_sizes, int n_in,
                              void* d_out, int out_size, void* d_ws, size_t ws_size,
                              hipStream_t stream) {
  const int* x = (const int*)d_in[0];
  const int* xc = (const int*)d_in[1];
  const int* self_loc = (const int*)d_in[2];
  const float* emb = (const float*)d_in[3];
  const float* W_rnn = (const float*)d_in[4];
  const float* U_rnn = (const float*)d_in[5];
  const float* b_rnn = (const float*)d_in[6];
  const float* wt_rnn = (const float*)d_in[7];
  const float* W_c = (const float*)d_in[8];
  const float* U_c = (const float*)d_in[9];
  const float* b_c = (const float*)d_in[10];
  const float* wt_c = (const float*)d_in[11];
  const float* Wv = (const float*)d_in[12];
  const float* bv = (const float*)d_in[13];
  const float* W0 = (const float*)d_in[14];
  const float* b0 = (const float*)d_in[15];
  const float* W1 = (const float*)d_in[16];
  const float* b1 = (const float*)d_in[17];
  const float* W2 = (const float*)d_in[18];
  const float* b2 = (const float*)d_in[19];
  const float* Wp = (const float*)d_in[20];
  const float* bp = (const float*)d_in[21];
  float* out = (float*)d_out;

  char* ws = (char*)d_ws;
  size_t cur = 0;
  auto alloc = [&](size_t bytes) {
    char* p = ws + cur;
    cur += (bytes + 255) & ~(size_t)255;
    return p;
  };
  float* xself = (float*)alloc((size_t)BB * DD * 4);
  float* dtc = (float*)alloc((size_t)128 * 128 * 4);
  float* hcont = (float*)alloc((size_t)BB * HH * 4);
  float* hh = (float*)alloc((size_t)BB * 1664 * 4);
  __bf16* hh_bf = (__bf16*)alloc((size_t)BB * 1664 * 2);
  __bf16* z0 = (__bf16*)alloc((size_t)BB * 1024 * 2);
  __bf16* z1 = (__bf16*)alloc((size_t)BB * 512 * 2);
  __bf16* z2 = (__bf16*)alloc((size_t)BB * 256 * 2);
  float* hmain = (float*)alloc((size_t)8192 * HH * 4);
  __hip_bfloat16* ec = (__hip_bfloat16*)alloc((size_t)16384 * DD * 2);
  __bf16* em = (__bf16*)alloc((size_t)KK * 8192 * DD * 2);
  __bf16* G2 = (__bf16*)alloc((size_t)16384 * 1024 * 2);
  __bf16* pWs = (__bf16*)alloc((size_t)4 * 48 * 64 * 8 * 2);
  __bf16* pWe = (__bf16*)alloc((size_t)4 * 48 * 64 * 8 * 2);
  __bf16* pU = (__bf16*)alloc((size_t)8 * 48 * 64 * 8 * 2);
  __bf16* pWc = (__bf16*)alloc((size_t)4 * 48 * 64 * 8 * 2);
  unsigned char* pU8 = (unsigned char*)alloc((size_t)8 * 48 * 64 * 8);
  __bf16* pW0 = (__bf16*)alloc((size_t)52 * 64 * 64 * 8 * 2);
  __bf16* pW1 = (__bf16*)alloc((size_t)32 * 32 * 64 * 8 * 2);
  __bf16* pW2 = (__bf16*)alloc((size_t)16 * 16 * 64 * 8 * 2);
  (void)ws_size;

  hipLaunchKernelGGL(k_build_cont, dim3(128, 128), dim3(128), 0, stream, xc, emb, ec, dtc);
  hipLaunchKernelGGL(k_pack, dim3(4, 48), dim3(64), 0, stream, W_c, pWc);
  hipLaunchKernelGGL(k_pack8, dim3(8, 48), dim3(64), 0, stream, U_c, pU8);
  hipLaunchKernelGGL(k_gemm_g, dim3(512), dim3(512), 0, stream, ec, pWc, b_c, G2);
  hipLaunchKernelGGL(k_pack, dim3(4, 48), dim3(64), 0, stream, W_rnn, pWs);
  hipLaunchKernelGGL(k_pack, dim3(4, 48), dim3(64), 0, stream, W_rnn + 128 * 768, pWe);
  hipLaunchKernelGGL(k_pack, dim3(8, 48), dim3(64), 0, stream, U_rnn, pU);
  hipLaunchKernelGGL(k_packN, dim3(52, 64), dim3(64), 0, stream, W0, pW0, 1024);
  hipLaunchKernelGGL(k_packN, dim3(32, 32), dim3(64), 0, stream, W1, pW1, 512);
  hipLaunchKernelGGL(k_packN, dim3(16, 16), dim3(64), 0, stream, W2, pW2, 256);
  hipLaunchKernelGGL(k_rnn_fused, dim3(264), dim3(512), 0, stream, G2, dtc, pU8, wt_c,
                     hcont, x, self_loc, emb, pWs, pWe, pU, b_rnn, wt_rnn, em, xself,
                     hmain);
  hipLaunchKernelGGL(k_att, dim3(BB), dim3(256), 0, stream, hmain, xself, hcont, Wv, bv, hh,
                     hh_bf);
  hipLaunchKernelGGL(k_mlp_mfma, dim3(4, 16), dim3(512), 0, stream, hh_bf, pW0, b0, z0,
                     1664, 1024);
  hipLaunchKernelGGL(k_mlp_mfma, dim3(2, 16), dim3(512), 0, stream, z0, pW1, b1, z1, 1024,
                     512);
  hipLaunchKernelGGL(k_mlp_mfma, dim3(1, 16), dim3(512), 0, stream, z1, pW2, b2, z2, 512,
                     256);
  hipLaunchKernelGGL(k_head, dim3(BB), dim3(64), 0, stream, z2, Wp, bp, out);
}